// Round 1
// baseline (1385.325 us; speedup 1.0000x reference)
//
#include <hip/hip_runtime.h>
#include <math.h>

constexpr int DIN = 256;
constexpr int HID = 128;
constexpr int LAT = 64;

__device__ __forceinline__ float4 ld4(const float* p) { return *reinterpret_cast<const float4*>(p); }
__device__ __forceinline__ void st4(float* p, float4 v) { *reinterpret_cast<float4*>(p) = v; }

// ---------------- generic f32 GEMM: C[M,N] = A[M,K] @ B[K,N] (+ crow[N]) ----------------
// BM=64, BN=64, BK=32, 256 threads, 4x4 per thread. N % 64 == 0, K % 32 == 0. M guarded.
__global__ __launch_bounds__(256) void gemm64(const float* __restrict__ A, const float* __restrict__ B,
                                              const float* __restrict__ crow, float* __restrict__ C,
                                              int M, int N, int K) {
  __shared__ float As[32][68];
  __shared__ float Bs[32][68];
  int t = threadIdx.x;
  int m0 = blockIdx.x * 64, n0 = blockIdx.y * 64;
  int tm = t & 15, tn = t >> 4;
  float acc[4][4];
#pragma unroll
  for (int i = 0; i < 4; i++)
#pragma unroll
    for (int j = 0; j < 4; j++) acc[i][j] = 0.f;

  for (int kt = 0; kt < K; kt += 32) {
#pragma unroll
    for (int i = 0; i < 2; ++i) {
      int f4 = t + i * 256;
      int m = f4 >> 3;
      int k4 = (f4 & 7) << 2;
      int gm = m0 + m;
      float4 v = make_float4(0.f, 0.f, 0.f, 0.f);
      if (gm < M) v = ld4(A + (size_t)gm * K + kt + k4);
      As[k4 + 0][m] = v.x; As[k4 + 1][m] = v.y; As[k4 + 2][m] = v.z; As[k4 + 3][m] = v.w;
    }
#pragma unroll
    for (int i = 0; i < 2; ++i) {
      int f4 = t + i * 256;
      int k = f4 >> 4;
      int n4 = (f4 & 15) << 2;
      float4 v = ld4(B + (size_t)(kt + k) * N + n0 + n4);
      st4(&Bs[k][n4], v);
    }
    __syncthreads();
#pragma unroll
    for (int k = 0; k < 32; ++k) {
      float4 a = ld4(&As[k][tm << 2]);
      float4 b = ld4(&Bs[k][tn << 2]);
      float av[4] = {a.x, a.y, a.z, a.w};
      float bv[4] = {b.x, b.y, b.z, b.w};
#pragma unroll
      for (int i = 0; i < 4; i++)
#pragma unroll
        for (int j = 0; j < 4; j++) acc[i][j] = fmaf(av[i], bv[j], acc[i][j]);
    }
    __syncthreads();
  }
#pragma unroll
  for (int i = 0; i < 4; ++i) {
    int gm = m0 + (tm << 2) + i;
    if (gm < M) {
      int nb = n0 + (tn << 2);
      float4 v = make_float4(acc[i][0], acc[i][1], acc[i][2], acc[i][3]);
      if (crow) { v.x += crow[nb]; v.y += crow[nb + 1]; v.z += crow[nb + 2]; v.w += crow[nb + 3]; }
      st4(C + (size_t)gm * N + nb, v);
    }
  }
}

// ---------------- attention scores: a_src[n,h] = <xp[n,h,:], att_src[h,:]> ----------------
__global__ __launch_bounds__(256) void attn_scores(const float* __restrict__ xp,
                                                   const float* __restrict__ att_src,
                                                   const float* __restrict__ att_dst,
                                                   float* __restrict__ a_src, float* __restrict__ a_dst, int N) {
  int wid = threadIdx.x >> 6, lane = threadIdx.x & 63;
  int n = blockIdx.x * 4 + wid;
  if (n >= N) return;
  int h = lane >> 5;
  int f4 = (lane & 31) << 2;
  float4 v = ld4(xp + (size_t)n * 256 + h * 128 + f4);
  float4 as = ld4(att_src + h * 128 + f4);
  float4 ad = ld4(att_dst + h * 128 + f4);
  float ps = v.x * as.x + v.y * as.y + v.z * as.z + v.w * as.w;
  float pd = v.x * ad.x + v.y * ad.y + v.z * ad.z + v.w * ad.w;
#pragma unroll
  for (int m = 16; m >= 1; m >>= 1) { ps += __shfl_xor(ps, m); pd += __shfl_xor(pd, m); }
  if ((lane & 31) == 0) { a_src[n * 2 + h] = ps; a_dst[n * 2 + h] = pd; }
}

// ---------------- CSR build ----------------
__global__ void deg_count(const int* __restrict__ ei, int E, int Et, int* __restrict__ deg) {
  int i = blockIdx.x * blockDim.x + threadIdx.x;
  if (i >= Et) return;
  int d = (i < E) ? ei[E + i] : (i - E);
  atomicAdd(&deg[d], 1);
}

__global__ __launch_bounds__(1024) void scan_offsets(const int* __restrict__ deg, int* __restrict__ offs,
                                                     int* __restrict__ cursor, float* __restrict__ dinv, int N) {
  __shared__ int sh[1024];
  int tid = threadIdx.x;
  int chunk = (N + 1023) >> 10;
  int s0 = tid * chunk, e0 = min(s0 + chunk, N);
  int s = 0;
  for (int i = s0; i < e0; ++i) s += deg[i];
  sh[tid] = s;
  __syncthreads();
  int own = s;
  for (int d = 1; d < 1024; d <<= 1) {
    int v = (tid >= d) ? sh[tid - d] : 0;
    __syncthreads();
    sh[tid] += v;
    __syncthreads();
  }
  int run = sh[tid] - own;
  for (int i = s0; i < e0; ++i) {
    offs[i] = run; cursor[i] = run;
    dinv[i] = rsqrtf((float)deg[i]);
    run += deg[i];
  }
}

__global__ void csr_fill(const int* __restrict__ ei, int E, int Et, int* __restrict__ cursor, int* __restrict__ csr) {
  int i = blockIdx.x * blockDim.x + threadIdx.x;
  if (i >= Et) return;
  int s, d;
  if (i < E) { s = ei[i]; d = ei[E + i]; } else { s = i - E; d = i - E; }
  int pos = atomicAdd(&cursor[d], 1);
  csr[pos] = s;
}

// ---------------- GAT softmax per dst node (wave per node) ----------------
__global__ __launch_bounds__(256) void gat_softmax(const int* __restrict__ offs, const int* __restrict__ deg,
                                                   const int* __restrict__ csr, const float* __restrict__ a_src,
                                                   const float* __restrict__ a_dst, float* __restrict__ alpha, int N) {
  int wid = threadIdx.x >> 6, lane = threadIdx.x & 63;
  int n = blockIdx.x * 4 + wid;
  if (n >= N) return;
  int off = offs[n], dg = deg[n];
  float ad0 = a_dst[n * 2], ad1 = a_dst[n * 2 + 1];
  float m0 = -1e30f, m1 = -1e30f;
  for (int k = lane; k < dg; k += 64) {
    int s = csr[off + k];
    float e0 = a_src[s * 2] + ad0; e0 = e0 >= 0.f ? e0 : 0.2f * e0;
    float e1 = a_src[s * 2 + 1] + ad1; e1 = e1 >= 0.f ? e1 : 0.2f * e1;
    m0 = fmaxf(m0, e0); m1 = fmaxf(m1, e1);
  }
#pragma unroll
  for (int m = 32; m >= 1; m >>= 1) { m0 = fmaxf(m0, __shfl_xor(m0, m)); m1 = fmaxf(m1, __shfl_xor(m1, m)); }
  float s0 = 0.f, s1 = 0.f;
  float2* al2 = (float2*)alpha;
  for (int k = lane; k < dg; k += 64) {
    int s = csr[off + k];
    float e0 = a_src[s * 2] + ad0; e0 = e0 >= 0.f ? e0 : 0.2f * e0;
    float e1 = a_src[s * 2 + 1] + ad1; e1 = e1 >= 0.f ? e1 : 0.2f * e1;
    float x0 = __expf(e0 - m0), x1 = __expf(e1 - m1);
    al2[off + k] = make_float2(x0, x1);
    s0 += x0; s1 += x1;
  }
#pragma unroll
  for (int m = 32; m >= 1; m >>= 1) { s0 += __shfl_xor(s0, m); s1 += __shfl_xor(s1, m); }
  float r0 = 1.f / s0, r1 = 1.f / s1;
  for (int k = lane; k < dg; k += 64) {
    float2 v = al2[off + k];
    al2[off + k] = make_float2(v.x * r0, v.y * r1);
  }
}

// ---------------- GAT aggregation (wave per node): h1 = relu(mean_heads(sum alpha*xp[src]) + bias) ----------------
__global__ __launch_bounds__(256) void gat_aggregate(const int* __restrict__ offs, const int* __restrict__ deg,
                                                     const int* __restrict__ csr, const float* __restrict__ alpha,
                                                     const float* __restrict__ xp, const float* __restrict__ bias,
                                                     float* __restrict__ h1, int N) {
  int wid = threadIdx.x >> 6, lane = threadIdx.x & 63;
  int n = blockIdx.x * 4 + wid;
  if (n >= N) return;
  int off = offs[n], dg = deg[n];
  float4 acc = make_float4(0.f, 0.f, 0.f, 0.f);
  int f4 = lane << 2;
  bool h0 = lane < 32;
  const float2* al2 = (const float2*)alpha;
  for (int k = 0; k < dg; ++k) {
    int s = csr[off + k];
    float2 al = al2[off + k];
    float a = h0 ? al.x : al.y;
    float4 v = ld4(xp + (size_t)s * 256 + f4);
    acc.x = fmaf(v.x, a, acc.x);
    acc.y = fmaf(v.y, a, acc.y);
    acc.z = fmaf(v.z, a, acc.z);
    acc.w = fmaf(v.w, a, acc.w);
  }
  float ox = __shfl_down(acc.x, 32);
  float oy = __shfl_down(acc.y, 32);
  float oz = __shfl_down(acc.z, 32);
  float ow = __shfl_down(acc.w, 32);
  if (h0) {
    float4 b = ld4(bias + f4);
    float4 o;
    o.x = fmaxf(0.f, (acc.x + ox) * 0.5f + b.x);
    o.y = fmaxf(0.f, (acc.y + oy) * 0.5f + b.y);
    o.z = fmaxf(0.f, (acc.z + oz) * 0.5f + b.z);
    o.w = fmaxf(0.f, (acc.w + ow) * 0.5f + b.w);
    st4(h1 + (size_t)n * 128 + f4, o);
  }
}

// ---------------- BatchNorm stats ----------------
template <int C>
__global__ __launch_bounds__(256) void bn_stats(const float* __restrict__ h, int N, float* __restrict__ P,
                                                float* __restrict__ PS) {
  constexpr int R = 256 / C;
  __shared__ float sh[256], sh2[256];
  int t = threadIdx.x;
  int c = t % C, r = t / C;
  float s = 0.f, ss = 0.f;
  for (int n = blockIdx.x * R + r; n < N; n += gridDim.x * R) {
    float v = h[(size_t)n * C + c];
    s += v; ss += v * v;
  }
  sh[t] = s; sh2[t] = ss;
  __syncthreads();
  if (r == 0) {
#pragma unroll
    for (int i = 1; i < R; ++i) { s += sh[i * C + c]; ss += sh2[i * C + c]; }
    P[blockIdx.x * C + c] = s;
    PS[blockIdx.x * C + c] = ss;
  }
}

template <int C>
__global__ void bn_reduce(const float* __restrict__ P, const float* __restrict__ PS, int G, int N,
                          const float* __restrict__ g, const float* __restrict__ b,
                          float* __restrict__ svec, float* __restrict__ tvec) {
  int c = threadIdx.x;
  if (c >= C) return;
  float s = 0.f, ss = 0.f;
  for (int i = 0; i < G; ++i) { s += P[i * C + c]; ss += PS[i * C + c]; }
  float mean = s / N;
  float var = ss / N - mean * mean;
  float sc = g[c] * rsqrtf(var + 1e-5f);
  svec[c] = sc;
  tvec[c] = b[c] - mean * sc;
}

// fold BN1 into gcn_W: Wf[k,j] = s[k]*W[k,j]; cvec[j] = sum_k t[k]*W[k,j]
__global__ __launch_bounds__(256) void fold_gcn(const float* __restrict__ W, const float* __restrict__ svec,
                                                const float* __restrict__ tvec, float* __restrict__ Wf,
                                                float* __restrict__ cvec) {
  int t = threadIdx.x;
  for (int i = t; i < 128 * 64; i += 256) {
    int k = i >> 6;
    Wf[i] = svec[k] * W[i];
  }
  if (t < 64) {
    float c = 0.f;
    for (int k = 0; k < 128; ++k) c += tvec[k] * W[k * 64 + t];
    cvec[t] = c;
  }
}

// fold BN2 into mu_W / lv_W (+ their biases)
__global__ __launch_bounds__(256) void fold_mulv(const float* __restrict__ Wmu, const float* __restrict__ mub,
                                                 const float* __restrict__ Wlv, const float* __restrict__ lvb,
                                                 const float* __restrict__ svec, const float* __restrict__ tvec,
                                                 float* __restrict__ Wmuf, float* __restrict__ cmu,
                                                 float* __restrict__ Wlvf, float* __restrict__ clv) {
  int t = threadIdx.x;
  for (int i = t; i < 4096; i += 256) {
    int k = i >> 6;
    Wmuf[i] = svec[k] * Wmu[i];
    Wlvf[i] = svec[k] * Wlv[i];
  }
  if (t < 64) {
    float cm = mub[t], cl = lvb[t];
    for (int k = 0; k < 64; ++k) { cm += tvec[k] * Wmu[k * 64 + t]; cl += tvec[k] * Wlv[k * 64 + t]; }
    cmu[t] = cm; clv[t] = cl;
  }
}

// ---------------- GCN aggregation (wave per node, lane = feature) ----------------
__global__ __launch_bounds__(256) void gcn_aggregate(const int* __restrict__ offs, const int* __restrict__ deg,
                                                     const int* __restrict__ csr, const float* __restrict__ xp2,
                                                     const float* __restrict__ dinv, const float* __restrict__ bias,
                                                     float* __restrict__ g2, int N) {
  int wid = threadIdx.x >> 6, lane = threadIdx.x & 63;
  int n = blockIdx.x * 4 + wid;
  if (n >= N) return;
  int off = offs[n], dg = deg[n];
  float acc = 0.f;
  for (int k = 0; k < dg; ++k) {
    int s = csr[off + k];
    acc = fmaf(xp2[(size_t)s * 64 + lane], dinv[s], acc);
  }
  float v = acc * dinv[n] + bias[lane];
  g2[(size_t)n * 64 + lane] = fmaxf(v, 0.f);
}

// ---------------- reparameterize ----------------
__global__ void reparam(const float* __restrict__ mu, const float* __restrict__ lv,
                        const float* __restrict__ eps, float* __restrict__ z, int total) {
  int i = blockIdx.x * blockDim.x + threadIdx.x;
  if (i >= total) return;
  z[i] = fmaf(eps[i], __expf(0.5f * lv[i]), mu[i]);
}

// ---------------- decoder: recon[e] = dec_b2 + sum_j relu(e_emb[e]@W1[:,j] + b1[j]) * W2[j] ----------------
// block = 64 edges. A (e_emb tile) k-major in LDS [128][64]; W1 staged in 4 k-tiles of [32][256].
__global__ __launch_bounds__(256) void decoder(const int* __restrict__ ei, int E,
                                               const float* __restrict__ rz, const float* __restrict__ W1,
                                               const float* __restrict__ b1, const float* __restrict__ W2,
                                               const float* __restrict__ b2, float* __restrict__ recon) {
  __shared__ float Als[128 * 64];
  __shared__ float Bls[32 * 256];
  int t = threadIdx.x;
  int e0 = blockIdx.x * 64;
  {
    int el = t >> 2;
    int part = t & 3;
    int e = min(e0 + el, E - 1);
    int r = (part < 2) ? ei[e] : ei[E + e];
    const float* src = rz + (size_t)r * 64 + (part & 1) * 32;
    int fbase = part * 32;
#pragma unroll
    for (int i = 0; i < 8; ++i) {
      float4 v = ld4(src + i * 4);
      int f = fbase + i * 4;
      Als[(f + 0) * 64 + el] = v.x;
      Als[(f + 1) * 64 + el] = v.y;
      Als[(f + 2) * 64 + el] = v.z;
      Als[(f + 3) * 64 + el] = v.w;
    }
  }
  int tj = t & 15, te = t >> 4;
  float acc[4][16];
#pragma unroll
  for (int a = 0; a < 4; a++)
#pragma unroll
    for (int b = 0; b < 16; b++) acc[a][b] = 0.f;

  for (int kt = 0; kt < 4; ++kt) {
    __syncthreads();
#pragma unroll
    for (int i = 0; i < 8; ++i) {
      int f4 = t + i * 256;
      int k = f4 >> 6;
      int c4 = (f4 & 63) << 2;
      float4 v = ld4(W1 + (size_t)(kt * 32 + k) * 256 + c4);
      st4(&Bls[k * 256 + c4], v);
    }
    __syncthreads();
#pragma unroll 4
    for (int k = 0; k < 32; ++k) {
      float4 a4 = ld4(&Als[(kt * 32 + k) * 64 + (te << 2)]);
      float av[4] = {a4.x, a4.y, a4.z, a4.w};
#pragma unroll
      for (int jj = 0; jj < 4; ++jj) {
        float4 b4 = ld4(&Bls[k * 256 + jj * 64 + (tj << 2)]);
        float bv[4] = {b4.x, b4.y, b4.z, b4.w};
#pragma unroll
        for (int a = 0; a < 4; ++a) {
#pragma unroll
          for (int ii = 0; ii < 4; ++ii)
            acc[a][jj * 4 + ii] = fmaf(av[a], bv[ii], acc[a][jj * 4 + ii]);
        }
      }
    }
  }
  // epilogue: relu + dot with W2, reduce over tj group
  float p[4] = {0.f, 0.f, 0.f, 0.f};
#pragma unroll
  for (int jj = 0; jj < 4; ++jj) {
    int j = jj * 64 + (tj << 2);
    float4 bb = ld4(b1 + j);
    float4 ww = ld4(W2 + j);
    float bv[4] = {bb.x, bb.y, bb.z, bb.w};
    float wv[4] = {ww.x, ww.y, ww.z, ww.w};
#pragma unroll
    for (int ii = 0; ii < 4; ++ii) {
#pragma unroll
      for (int a = 0; a < 4; ++a) {
        float hd = fmaxf(acc[a][jj * 4 + ii] + bv[ii], 0.f);
        p[a] = fmaf(hd, wv[ii], p[a]);
      }
    }
  }
#pragma unroll
  for (int m = 8; m >= 1; m >>= 1) {
    p[0] += __shfl_xor(p[0], m);
    p[1] += __shfl_xor(p[1], m);
    p[2] += __shfl_xor(p[2], m);
    p[3] += __shfl_xor(p[3], m);
  }
  if (tj == 0) {
    float bb2 = b2[0];
    int eb = e0 + (te << 2);
    if (eb + 3 < E) {
      st4(recon + eb, make_float4(p[0] + bb2, p[1] + bb2, p[2] + bb2, p[3] + bb2));
    } else {
      for (int a = 0; a < 4; ++a)
        if (eb + a < E) recon[eb + a] = p[a] + bb2;
    }
  }
}

extern "C" void kernel_launch(void* const* d_in, const int* in_sizes, int n_in,
                              void* d_out, int out_size, void* d_ws, size_t ws_size,
                              hipStream_t stream) {
  const float* x = (const float*)d_in[0];
  const int* ei = (const int*)d_in[1];
  const float* gat_W = (const float*)d_in[2];
  const float* att_src = (const float*)d_in[3];
  const float* att_dst = (const float*)d_in[4];
  const float* gat_bias = (const float*)d_in[5];
  const float* bn1_g = (const float*)d_in[6];
  const float* bn1_b = (const float*)d_in[7];
  const float* gcn_W = (const float*)d_in[8];
  const float* gcn_bias = (const float*)d_in[9];
  const float* bn2_g = (const float*)d_in[10];
  const float* bn2_b = (const float*)d_in[11];
  const float* mu_W = (const float*)d_in[12];
  const float* mu_b = (const float*)d_in[13];
  const float* lv_W = (const float*)d_in[14];
  const float* lv_b = (const float*)d_in[15];
  const float* res_W = (const float*)d_in[16];
  const float* res_b = (const float*)d_in[17];
  const float* dec_W1 = (const float*)d_in[18];
  const float* dec_b1 = (const float*)d_in[19];
  const float* dec_W2 = (const float*)d_in[20];
  const float* dec_b2 = (const float*)d_in[21];
  const float* eps = (const float*)d_in[22];

  int N = in_sizes[0] / DIN;   // 50000
  int E = in_sizes[1] / 2;     // 800000
  int Et = E + N;

  float* ws = (float*)d_ws;
  size_t off = 0;
  // Region A: xp [N,256]; reused later for xp2/g2/z/res_z (each [N,64])
  float* xp = ws; off += (size_t)N * 256;
  float* xp2 = xp;
  float* g2 = xp + (size_t)N * 64;
  float* zb = xp + (size_t)N * 128;
  float* rz = xp + (size_t)N * 192;
  float* h1 = ws + off; off += (size_t)N * 128;
  float* a_src = ws + off; off += (size_t)2 * N;
  float* a_dst = ws + off; off += (size_t)2 * N;
  float* alpha = ws + off; off += (size_t)Et * 2;
  float* dinv = ws + off; off += N;
  float* P = ws + off; off += 128 * 128;
  float* PS = ws + off; off += 128 * 128;
  float* svec = ws + off; off += 128;
  float* tvec = ws + off; off += 128;
  float* W2f = ws + off; off += 128 * 64;
  float* c2 = ws + off; off += 64;
  float* Wmuf = ws + off; off += 64 * 64;
  float* cmu = ws + off; off += 64;
  float* Wlvf = ws + off; off += 64 * 64;
  float* clv = ws + off; off += 64;
  int* deg = (int*)(ws + off); off += N;
  int* offs = (int*)(ws + off); off += N;
  int* cursor = (int*)(ws + off); off += N;
  int* csr = (int*)(ws + off); off += Et;

  float* recon = (float*)d_out;
  float* mu = recon + E;
  float* lv = mu + (size_t)N * LAT;

  // 1. xp = x @ gat_W  [N,256]
  dim3 gA((N + 63) / 64, DIN / 64);
  gemm64<<<gA, 256, 0, stream>>>(x, gat_W, nullptr, xp, N, DIN, DIN);

  // 2. attention scores
  attn_scores<<<(N + 3) / 4, 256, 0, stream>>>(xp, att_src, att_dst, a_src, a_dst, N);

  // 3. CSR build (edges + self loops)
  hipMemsetAsync(deg, 0, (size_t)N * sizeof(int), stream);
  deg_count<<<(Et + 255) / 256, 256, 0, stream>>>(ei, E, Et, deg);
  scan_offsets<<<1, 1024, 0, stream>>>(deg, offs, cursor, dinv, N);
  csr_fill<<<(Et + 255) / 256, 256, 0, stream>>>(ei, E, Et, cursor, csr);

  // 4. GAT softmax + aggregation → h1 = relu(gat_out)
  gat_softmax<<<(N + 3) / 4, 256, 0, stream>>>(offs, deg, csr, a_src, a_dst, alpha, N);
  gat_aggregate<<<(N + 3) / 4, 256, 0, stream>>>(offs, deg, csr, alpha, xp, gat_bias, h1, N);

  // 5. BN1 folded into GCN weights; xp2 = h1 @ W2f + c2
  bn_stats<128><<<128, 256, 0, stream>>>(h1, N, P, PS);
  bn_reduce<128><<<1, 128, 0, stream>>>(P, PS, 128, N, bn1_g, bn1_b, svec, tvec);
  fold_gcn<<<1, 256, 0, stream>>>(gcn_W, svec, tvec, W2f, c2);
  dim3 gB((N + 63) / 64, 1);
  gemm64<<<gB, 256, 0, stream>>>(h1, W2f, c2, xp2, N, 64, 128);

  // 6. GCN aggregation → g2 = relu(...)
  gcn_aggregate<<<(N + 3) / 4, 256, 0, stream>>>(offs, deg, csr, xp2, dinv, gcn_bias, g2, N);

  // 7. BN2 folded into mu/lv weights; mu/lv GEMMs write straight into d_out
  bn_stats<64><<<128, 256, 0, stream>>>(g2, N, P, PS);
  bn_reduce<64><<<1, 64, 0, stream>>>(P, PS, 128, N, bn2_g, bn2_b, svec, tvec);
  fold_mulv<<<1, 256, 0, stream>>>(mu_W, mu_b, lv_W, lv_b, svec, tvec, Wmuf, cmu, Wlvf, clv);
  gemm64<<<gB, 256, 0, stream>>>(g2, Wmuf, cmu, mu, N, 64, 64);
  gemm64<<<gB, 256, 0, stream>>>(g2, Wlvf, clv, lv, N, 64, 64);

  // 8. z = mu + eps*exp(0.5*lv); res_z = z @ res_W + res_b
  reparam<<<(N * 64 + 255) / 256, 256, 0, stream>>>(mu, lv, eps, zb, N * 64);
  gemm64<<<gB, 256, 0, stream>>>(zb, res_W, res_b, rz, N, 64, 64);

  // 9. decoder MLP per edge
  decoder<<<(E + 63) / 64, 256, 0, stream>>>(ei, E, rz, dec_W1, dec_b1, dec_W2, dec_b2, recon);
}

// Round 2
// 869.175 us; speedup vs baseline: 1.5938x; 1.5938x over previous
//
#include <hip/hip_runtime.h>
#include <math.h>

constexpr int DIN = 256;
constexpr int HID = 128;
constexpr int LAT = 64;

typedef short bfrag __attribute__((ext_vector_type(8)));   // 8 bf16 (4 VGPRs)
typedef float f32x4 __attribute__((ext_vector_type(4)));

__device__ __forceinline__ float4 ld4(const float* p) { return *reinterpret_cast<const float4*>(p); }
__device__ __forceinline__ void st4(float* p, float4 v) { *reinterpret_cast<float4*>(p) = v; }

__device__ __forceinline__ unsigned short f2bf(float f) {
  unsigned int u = __float_as_uint(f);
  unsigned int r = (u + 0x7FFFu + ((u >> 16) & 1u)) >> 16;  // RNE
  return (unsigned short)r;
}

// ---------------- generic f32 GEMM: C[M,N] = A[M,K] @ B[K,N] (+ crow[N]) ----------------
__global__ __launch_bounds__(256) void gemm64(const float* __restrict__ A, const float* __restrict__ B,
                                              const float* __restrict__ crow, float* __restrict__ C,
                                              int M, int N, int K) {
  __shared__ float As[32][68];
  __shared__ float Bs[32][68];
  int t = threadIdx.x;
  int m0 = blockIdx.x * 64, n0 = blockIdx.y * 64;
  int tm = t & 15, tn = t >> 4;
  float acc[4][4];
#pragma unroll
  for (int i = 0; i < 4; i++)
#pragma unroll
    for (int j = 0; j < 4; j++) acc[i][j] = 0.f;

  for (int kt = 0; kt < K; kt += 32) {
#pragma unroll
    for (int i = 0; i < 2; ++i) {
      int f4 = t + i * 256;
      int m = f4 >> 3;
      int k4 = (f4 & 7) << 2;
      int gm = m0 + m;
      float4 v = make_float4(0.f, 0.f, 0.f, 0.f);
      if (gm < M) v = ld4(A + (size_t)gm * K + kt + k4);
      As[k4 + 0][m] = v.x; As[k4 + 1][m] = v.y; As[k4 + 2][m] = v.z; As[k4 + 3][m] = v.w;
    }
#pragma unroll
    for (int i = 0; i < 2; ++i) {
      int f4 = t + i * 256;
      int k = f4 >> 4;
      int n4 = (f4 & 15) << 2;
      float4 v = ld4(B + (size_t)(kt + k) * N + n0 + n4);
      st4(&Bs[k][n4], v);
    }
    __syncthreads();
#pragma unroll
    for (int k = 0; k < 32; ++k) {
      float4 a = ld4(&As[k][tm << 2]);
      float4 b = ld4(&Bs[k][tn << 2]);
      float av[4] = {a.x, a.y, a.z, a.w};
      float bv[4] = {b.x, b.y, b.z, b.w};
#pragma unroll
      for (int i = 0; i < 4; i++)
#pragma unroll
        for (int j = 0; j < 4; j++) acc[i][j] = fmaf(av[i], bv[j], acc[i][j]);
    }
    __syncthreads();
  }
#pragma unroll
  for (int i = 0; i < 4; ++i) {
    int gm = m0 + (tm << 2) + i;
    if (gm < M) {
      int nb = n0 + (tn << 2);
      float4 v = make_float4(acc[i][0], acc[i][1], acc[i][2], acc[i][3]);
      if (crow) { v.x += crow[nb]; v.y += crow[nb + 1]; v.z += crow[nb + 2]; v.w += crow[nb + 3]; }
      st4(C + (size_t)gm * N + nb, v);
    }
  }
}

// ---------------- attention scores ----------------
__global__ __launch_bounds__(256) void attn_scores(const float* __restrict__ xp,
                                                   const float* __restrict__ att_src,
                                                   const float* __restrict__ att_dst,
                                                   float* __restrict__ a_src, float* __restrict__ a_dst, int N) {
  int wid = threadIdx.x >> 6, lane = threadIdx.x & 63;
  int n = blockIdx.x * 4 + wid;
  if (n >= N) return;
  int h = lane >> 5;
  int f4 = (lane & 31) << 2;
  float4 v = ld4(xp + (size_t)n * 256 + h * 128 + f4);
  float4 as = ld4(att_src + h * 128 + f4);
  float4 ad = ld4(att_dst + h * 128 + f4);
  float ps = v.x * as.x + v.y * as.y + v.z * as.z + v.w * as.w;
  float pd = v.x * ad.x + v.y * ad.y + v.z * ad.z + v.w * ad.w;
#pragma unroll
  for (int m = 16; m >= 1; m >>= 1) { ps += __shfl_xor(ps, m); pd += __shfl_xor(pd, m); }
  if ((lane & 31) == 0) { a_src[n * 2 + h] = ps; a_dst[n * 2 + h] = pd; }
}

// ---------------- CSR build ----------------
__global__ void deg_count(const int* __restrict__ ei, int E, int Et, int* __restrict__ deg) {
  int i = blockIdx.x * blockDim.x + threadIdx.x;
  if (i >= Et) return;
  int d = (i < E) ? ei[E + i] : (i - E);
  atomicAdd(&deg[d], 1);
}

__global__ __launch_bounds__(1024) void scan_offsets(const int* __restrict__ deg, int* __restrict__ offs,
                                                     int* __restrict__ cursor, float* __restrict__ dinv, int N) {
  __shared__ int sh[1024];
  int tid = threadIdx.x;
  int chunk = (N + 1023) >> 10;
  int s0 = tid * chunk, e0 = min(s0 + chunk, N);
  int s = 0;
  for (int i = s0; i < e0; ++i) s += deg[i];
  sh[tid] = s;
  __syncthreads();
  int own = s;
  for (int d = 1; d < 1024; d <<= 1) {
    int v = (tid >= d) ? sh[tid - d] : 0;
    __syncthreads();
    sh[tid] += v;
    __syncthreads();
  }
  int run = sh[tid] - own;
  for (int i = s0; i < e0; ++i) {
    offs[i] = run; cursor[i] = run;
    dinv[i] = rsqrtf((float)deg[i]);
    run += deg[i];
  }
}

__global__ void csr_fill(const int* __restrict__ ei, int E, int Et, int* __restrict__ cursor, int* __restrict__ csr) {
  int i = blockIdx.x * blockDim.x + threadIdx.x;
  if (i >= Et) return;
  int s, d;
  if (i < E) { s = ei[i]; d = ei[E + i]; } else { s = i - E; d = i - E; }
  int pos = atomicAdd(&cursor[d], 1);
  csr[pos] = s;
}

// ---------------- GAT softmax per dst node (wave per node) ----------------
__global__ __launch_bounds__(256) void gat_softmax(const int* __restrict__ offs, const int* __restrict__ deg,
                                                   const int* __restrict__ csr, const float* __restrict__ a_src,
                                                   const float* __restrict__ a_dst, float* __restrict__ alpha, int N) {
  int wid = threadIdx.x >> 6, lane = threadIdx.x & 63;
  int n = blockIdx.x * 4 + wid;
  if (n >= N) return;
  int off = offs[n], dg = deg[n];
  float ad0 = a_dst[n * 2], ad1 = a_dst[n * 2 + 1];
  float m0 = -1e30f, m1 = -1e30f;
  for (int k = lane; k < dg; k += 64) {
    int s = csr[off + k];
    float e0 = a_src[s * 2] + ad0; e0 = e0 >= 0.f ? e0 : 0.2f * e0;
    float e1 = a_src[s * 2 + 1] + ad1; e1 = e1 >= 0.f ? e1 : 0.2f * e1;
    m0 = fmaxf(m0, e0); m1 = fmaxf(m1, e1);
  }
#pragma unroll
  for (int m = 32; m >= 1; m >>= 1) { m0 = fmaxf(m0, __shfl_xor(m0, m)); m1 = fmaxf(m1, __shfl_xor(m1, m)); }
  float s0 = 0.f, s1 = 0.f;
  float2* al2 = (float2*)alpha;
  for (int k = lane; k < dg; k += 64) {
    int s = csr[off + k];
    float e0 = a_src[s * 2] + ad0; e0 = e0 >= 0.f ? e0 : 0.2f * e0;
    float e1 = a_src[s * 2 + 1] + ad1; e1 = e1 >= 0.f ? e1 : 0.2f * e1;
    float x0 = __expf(e0 - m0), x1 = __expf(e1 - m1);
    al2[off + k] = make_float2(x0, x1);
    s0 += x0; s1 += x1;
  }
#pragma unroll
  for (int m = 32; m >= 1; m >>= 1) { s0 += __shfl_xor(s0, m); s1 += __shfl_xor(s1, m); }
  float r0 = 1.f / s0, r1 = 1.f / s1;
  for (int k = lane; k < dg; k += 64) {
    float2 v = al2[off + k];
    al2[off + k] = make_float2(v.x * r0, v.y * r1);
  }
}

// ---------------- GAT aggregation (wave per node) ----------------
__global__ __launch_bounds__(256) void gat_aggregate(const int* __restrict__ offs, const int* __restrict__ deg,
                                                     const int* __restrict__ csr, const float* __restrict__ alpha,
                                                     const float* __restrict__ xp, const float* __restrict__ bias,
                                                     float* __restrict__ h1, int N) {
  int wid = threadIdx.x >> 6, lane = threadIdx.x & 63;
  int n = blockIdx.x * 4 + wid;
  if (n >= N) return;
  int off = offs[n], dg = deg[n];
  float4 acc = make_float4(0.f, 0.f, 0.f, 0.f);
  int f4 = lane << 2;
  bool h0 = lane < 32;
  const float2* al2 = (const float2*)alpha;
  for (int k = 0; k < dg; ++k) {
    int s = csr[off + k];
    float2 al = al2[off + k];
    float a = h0 ? al.x : al.y;
    float4 v = ld4(xp + (size_t)s * 256 + f4);
    acc.x = fmaf(v.x, a, acc.x);
    acc.y = fmaf(v.y, a, acc.y);
    acc.z = fmaf(v.z, a, acc.z);
    acc.w = fmaf(v.w, a, acc.w);
  }
  float ox = __shfl_down(acc.x, 32);
  float oy = __shfl_down(acc.y, 32);
  float oz = __shfl_down(acc.z, 32);
  float ow = __shfl_down(acc.w, 32);
  if (h0) {
    float4 b = ld4(bias + f4);
    float4 o;
    o.x = fmaxf(0.f, (acc.x + ox) * 0.5f + b.x);
    o.y = fmaxf(0.f, (acc.y + oy) * 0.5f + b.y);
    o.z = fmaxf(0.f, (acc.z + oz) * 0.5f + b.z);
    o.w = fmaxf(0.f, (acc.w + ow) * 0.5f + b.w);
    st4(h1 + (size_t)n * 128 + f4, o);
  }
}

// ---------------- BatchNorm stats ----------------
template <int C>
__global__ __launch_bounds__(256) void bn_stats(const float* __restrict__ h, int N, float* __restrict__ P,
                                                float* __restrict__ PS) {
  constexpr int R = 256 / C;
  __shared__ float sh[256], sh2[256];
  int t = threadIdx.x;
  int c = t % C, r = t / C;
  float s = 0.f, ss = 0.f;
  for (int n = blockIdx.x * R + r; n < N; n += gridDim.x * R) {
    float v = h[(size_t)n * C + c];
    s += v; ss += v * v;
  }
  sh[t] = s; sh2[t] = ss;
  __syncthreads();
  if (r == 0) {
#pragma unroll
    for (int i = 1; i < R; ++i) { s += sh[i * C + c]; ss += sh2[i * C + c]; }
    P[blockIdx.x * C + c] = s;
    PS[blockIdx.x * C + c] = ss;
  }
}

template <int C>
__global__ void bn_reduce(const float* __restrict__ P, const float* __restrict__ PS, int G, int N,
                          const float* __restrict__ g, const float* __restrict__ b,
                          float* __restrict__ svec, float* __restrict__ tvec) {
  int c = threadIdx.x;
  if (c >= C) return;
  float s = 0.f, ss = 0.f;
  for (int i = 0; i < G; ++i) { s += P[i * C + c]; ss += PS[i * C + c]; }
  float mean = s / N;
  float var = ss / N - mean * mean;
  float sc = g[c] * rsqrtf(var + 1e-5f);
  svec[c] = sc;
  tvec[c] = b[c] - mean * sc;
}

__global__ __launch_bounds__(256) void fold_gcn(const float* __restrict__ W, const float* __restrict__ svec,
                                                const float* __restrict__ tvec, float* __restrict__ Wf,
                                                float* __restrict__ cvec) {
  int t = threadIdx.x;
  for (int i = t; i < 128 * 64; i += 256) {
    int k = i >> 6;
    Wf[i] = svec[k] * W[i];
  }
  if (t < 64) {
    float c = 0.f;
    for (int k = 0; k < 128; ++k) c += tvec[k] * W[k * 64 + t];
    cvec[t] = c;
  }
}

__global__ __launch_bounds__(256) void fold_mulv(const float* __restrict__ Wmu, const float* __restrict__ mub,
                                                 const float* __restrict__ Wlv, const float* __restrict__ lvb,
                                                 const float* __restrict__ svec, const float* __restrict__ tvec,
                                                 float* __restrict__ Wmuf, float* __restrict__ cmu,
                                                 float* __restrict__ Wlvf, float* __restrict__ clv) {
  int t = threadIdx.x;
  for (int i = t; i < 4096; i += 256) {
    int k = i >> 6;
    Wmuf[i] = svec[k] * Wmu[i];
    Wlvf[i] = svec[k] * Wlv[i];
  }
  if (t < 64) {
    float cm = mub[t], cl = lvb[t];
    for (int k = 0; k < 64; ++k) { cm += tvec[k] * Wmu[k * 64 + t]; cl += tvec[k] * Wlv[k * 64 + t]; }
    cmu[t] = cm; clv[t] = cl;
  }
}

// ---------------- GCN aggregation ----------------
__global__ __launch_bounds__(256) void gcn_aggregate(const int* __restrict__ offs, const int* __restrict__ deg,
                                                     const int* __restrict__ csr, const float* __restrict__ xp2,
                                                     const float* __restrict__ dinv, const float* __restrict__ bias,
                                                     float* __restrict__ g2, int N) {
  int wid = threadIdx.x >> 6, lane = threadIdx.x & 63;
  int n = blockIdx.x * 4 + wid;
  if (n >= N) return;
  int off = offs[n], dg = deg[n];
  float acc = 0.f;
  for (int k = 0; k < dg; ++k) {
    int s = csr[off + k];
    acc = fmaf(xp2[(size_t)s * 64 + lane], dinv[s], acc);
  }
  float v = acc * dinv[n] + bias[lane];
  g2[(size_t)n * 64 + lane] = fmaxf(v, 0.f);
}

// ---------------- reparameterize ----------------
__global__ void reparam(const float* __restrict__ mu, const float* __restrict__ lv,
                        const float* __restrict__ eps, float* __restrict__ z, int total) {
  int i = blockIdx.x * blockDim.x + threadIdx.x;
  if (i >= total) return;
  z[i] = fmaf(eps[i], __expf(0.5f * lv[i]), mu[i]);
}

// ---------------- bf16 conversion of res_z ----------------
__global__ void cvt_bf16(const float* __restrict__ in, unsigned short* __restrict__ out, int n4) {
  int i = blockIdx.x * blockDim.x + threadIdx.x;
  if (i >= n4) return;
  float4 v = ((const float4*)in)[i];
  ushort4 o;
  o.x = f2bf(v.x); o.y = f2bf(v.y); o.z = f2bf(v.z); o.w = f2bf(v.w);
  ((ushort4*)out)[i] = o;
}

// ---------------- prep W1 → bf16 decoder-ready layout [4 kt][256 j][40 kp] ----------------
__global__ void prep_W1(const float* __restrict__ W1, unsigned short* __restrict__ W1t) {
  int i = blockIdx.x * blockDim.x + threadIdx.x;
  if (i >= 4 * 256 * 40) return;
  int kt = i / 10240;
  int rem = i - kt * 10240;
  int j = rem / 40;
  int kp = rem - j * 40;
  float v = (kp < 32) ? W1[(size_t)(kt * 32 + kp) * 256 + j] : 0.f;
  W1t[i] = f2bf(v);
}

// ---------------- MFMA decoder ----------------
// block = 64 edges, 256 threads (4 waves), BN=256 (wave w: j in [64w,64w+64)), K=128.
// A: LDS [64 e][128 k] bf16, row-major 256B/row, XOR-swizzled (byte ^= (e&7)<<4).
// B: LDS [256 j][40 kp] bf16 (80B/row, k-padded) staged per K-tile from pre-transposed W1t.
__global__ __launch_bounds__(256) void decoder_mfma(const int* __restrict__ ei, int E,
                                                    const unsigned short* __restrict__ rzb,
                                                    const unsigned short* __restrict__ W1t,
                                                    const float* __restrict__ b1, const float* __restrict__ W2,
                                                    const float* __restrict__ b2, float* __restrict__ recon) {
  __shared__ unsigned short Als[64 * 128];   // 16 KB
  __shared__ unsigned short Bls[256 * 40];   // 20 KB
  __shared__ float red[4][64];
  int t = threadIdx.x;
  int wv = t >> 6, l = t & 63;
  int lg = l >> 4, ll = l & 15;
  int e0 = blockIdx.x * 64;

  // ---- stage A: gather e_emb rows (bf16), swizzled ----
  {
    int e = t >> 2;                 // edge in tile
    int part = (t >> 1) & 1;        // 0: src node (k 0..63), 1: dst node (k 64..127)
    int half = t & 1;               // 64B half of the 128B row-part
    int eg = e0 + e;
    if (eg >= E) eg = E - 1;
    int r = (part == 0) ? ei[eg] : ei[E + eg];
    const uint4* gsrc = (const uint4*)(rzb + (size_t)r * 64 + half * 32);
    int bo0 = part * 128 + half * 64;
    int swz = (e & 7) << 4;
#pragma unroll
    for (int c = 0; c < 4; ++c) {
      uint4 v = gsrc[c];
      int bo = bo0 + c * 16;
      *(uint4*)&Als[e * 128 + ((bo ^ swz) >> 1)] = v;
    }
  }

  f32x4 acc[4][4];
#pragma unroll
  for (int a = 0; a < 4; ++a)
#pragma unroll
    for (int b = 0; b < 4; ++b) acc[a][b] = (f32x4){0.f, 0.f, 0.f, 0.f};

  for (int kt = 0; kt < 4; ++kt) {
    __syncthreads();
    // stage B k-tile: contiguous 20480B copy
    {
      const uint4* gsrc = (const uint4*)(W1t + kt * 10240);
      uint4* ldst = (uint4*)Bls;
#pragma unroll
      for (int i = 0; i < 5; ++i) ldst[t + i * 256] = gsrc[t + i * 256];
    }
    __syncthreads();

    // A fragments for this k-tile: lane l -> edge fm*16+ll, k = kt*32 + lg*8 + [0..7]
    bfrag af[4];
#pragma unroll
    for (int fm = 0; fm < 4; ++fm) {
      int e = fm * 16 + ll;
      int bo = kt * 64 + lg * 16;
      af[fm] = *(const bfrag*)&Als[e * 128 + ((bo ^ ((e & 7) << 4)) >> 1)];
    }
#pragma unroll
    for (int fn = 0; fn < 4; ++fn) {
      int j = wv * 64 + fn * 16 + ll;
      bfrag bf = *(const bfrag*)&Bls[j * 40 + lg * 8];
#pragma unroll
      for (int fm = 0; fm < 4; ++fm)
        acc[fm][fn] = __builtin_amdgcn_mfma_f32_16x16x32_bf16(af[fm], bf, acc[fm][fn], 0, 0, 0);
    }
  }

  // ---- epilogue: relu + W2 dot, reduce ----
  float bj[4], wj[4];
#pragma unroll
  for (int fn = 0; fn < 4; ++fn) {
    int j = wv * 64 + fn * 16 + ll;
    bj[fn] = b1[j];
    wj[fn] = W2[j];
  }
#pragma unroll
  for (int fm = 0; fm < 4; ++fm) {
    float pr[4] = {0.f, 0.f, 0.f, 0.f};
#pragma unroll
    for (int fn = 0; fn < 4; ++fn) {
#pragma unroll
      for (int r = 0; r < 4; ++r)
        pr[r] = fmaf(fmaxf(acc[fm][fn][r] + bj[fn], 0.f), wj[fn], pr[r]);
    }
#pragma unroll
    for (int m = 8; m >= 1; m >>= 1) {
#pragma unroll
      for (int r = 0; r < 4; ++r) pr[r] += __shfl_xor(pr[r], m);
    }
    if (ll == 0) {
#pragma unroll
      for (int r = 0; r < 4; ++r) red[wv][fm * 16 + lg * 4 + r] = pr[r];
    }
  }
  __syncthreads();
  if (t < 64) {
    int eg = e0 + t;
    if (eg < E) recon[eg] = red[0][t] + red[1][t] + red[2][t] + red[3][t] + b2[0];
  }
}

extern "C" void kernel_launch(void* const* d_in, const int* in_sizes, int n_in,
                              void* d_out, int out_size, void* d_ws, size_t ws_size,
                              hipStream_t stream) {
  const float* x = (const float*)d_in[0];
  const int* ei = (const int*)d_in[1];
  const float* gat_W = (const float*)d_in[2];
  const float* att_src = (const float*)d_in[3];
  const float* att_dst = (const float*)d_in[4];
  const float* gat_bias = (const float*)d_in[5];
  const float* bn1_g = (const float*)d_in[6];
  const float* bn1_b = (const float*)d_in[7];
  const float* gcn_W = (const float*)d_in[8];
  const float* gcn_bias = (const float*)d_in[9];
  const float* bn2_g = (const float*)d_in[10];
  const float* bn2_b = (const float*)d_in[11];
  const float* mu_W = (const float*)d_in[12];
  const float* mu_b = (const float*)d_in[13];
  const float* lv_W = (const float*)d_in[14];
  const float* lv_b = (const float*)d_in[15];
  const float* res_W = (const float*)d_in[16];
  const float* res_b = (const float*)d_in[17];
  const float* dec_W1 = (const float*)d_in[18];
  const float* dec_b1 = (const float*)d_in[19];
  const float* dec_W2 = (const float*)d_in[20];
  const float* dec_b2 = (const float*)d_in[21];
  const float* eps = (const float*)d_in[22];

  int N = in_sizes[0] / DIN;   // 50000
  int E = in_sizes[1] / 2;     // 800000
  int Et = E + N;

  float* ws = (float*)d_ws;
  size_t off = 0;
  float* xp = ws; off += (size_t)N * 256;
  float* xp2 = xp;
  float* g2 = xp + (size_t)N * 64;
  float* zb = xp + (size_t)N * 128;
  float* rz = xp + (size_t)N * 192;
  unsigned short* rzb = (unsigned short*)zb;   // z dead after rz GEMM; reuse for bf16 rz
  float* h1 = ws + off; off += (size_t)N * 128;
  float* a_src = ws + off; off += (size_t)2 * N;
  float* a_dst = ws + off; off += (size_t)2 * N;
  float* alpha = ws + off; off += (size_t)Et * 2;
  float* dinv = ws + off; off += N;
  float* P = ws + off; off += 128 * 128;
  float* PS = ws + off; off += 128 * 128;
  float* svec = ws + off; off += 128;
  float* tvec = ws + off; off += 128;
  float* W2f = ws + off; off += 128 * 64;
  float* c2 = ws + off; off += 64;
  float* Wmuf = ws + off; off += 64 * 64;
  float* cmu = ws + off; off += 64;
  float* Wlvf = ws + off; off += 64 * 64;
  float* clv = ws + off; off += 64;
  unsigned short* W1t = (unsigned short*)(ws + off); off += 20480;  // 4*256*40 bf16
  int* deg = (int*)(ws + off); off += N;
  int* offs = (int*)(ws + off); off += N;
  int* cursor = (int*)(ws + off); off += N;
  int* csr = (int*)(ws + off); off += Et;

  float* recon = (float*)d_out;
  float* mu = recon + E;
  float* lv = mu + (size_t)N * LAT;

  // 0. prep W1 (independent, do early)
  prep_W1<<<(4 * 256 * 40 + 255) / 256, 256, 0, stream>>>(dec_W1, W1t);

  // 1. xp = x @ gat_W
  dim3 gA((N + 63) / 64, DIN / 64);
  gemm64<<<gA, 256, 0, stream>>>(x, gat_W, nullptr, xp, N, DIN, DIN);

  // 2. attention scores
  attn_scores<<<(N + 3) / 4, 256, 0, stream>>>(xp, att_src, att_dst, a_src, a_dst, N);

  // 3. CSR build
  hipMemsetAsync(deg, 0, (size_t)N * sizeof(int), stream);
  deg_count<<<(Et + 255) / 256, 256, 0, stream>>>(ei, E, Et, deg);
  scan_offsets<<<1, 1024, 0, stream>>>(deg, offs, cursor, dinv, N);
  csr_fill<<<(Et + 255) / 256, 256, 0, stream>>>(ei, E, Et, cursor, csr);

  // 4. GAT softmax + aggregation
  gat_softmax<<<(N + 3) / 4, 256, 0, stream>>>(offs, deg, csr, a_src, a_dst, alpha, N);
  gat_aggregate<<<(N + 3) / 4, 256, 0, stream>>>(offs, deg, csr, alpha, xp, gat_bias, h1, N);

  // 5. BN1 folded into GCN weights
  bn_stats<128><<<128, 256, 0, stream>>>(h1, N, P, PS);
  bn_reduce<128><<<1, 128, 0, stream>>>(P, PS, 128, N, bn1_g, bn1_b, svec, tvec);
  fold_gcn<<<1, 256, 0, stream>>>(gcn_W, svec, tvec, W2f, c2);
  dim3 gB((N + 63) / 64, 1);
  gemm64<<<gB, 256, 0, stream>>>(h1, W2f, c2, xp2, N, 64, 128);

  // 6. GCN aggregation
  gcn_aggregate<<<(N + 3) / 4, 256, 0, stream>>>(offs, deg, csr, xp2, dinv, gcn_bias, g2, N);

  // 7. BN2 folded into mu/lv
  bn_stats<64><<<128, 256, 0, stream>>>(g2, N, P, PS);
  bn_reduce<64><<<1, 64, 0, stream>>>(P, PS, 128, N, bn2_g, bn2_b, svec, tvec);
  fold_mulv<<<1, 256, 0, stream>>>(mu_W, mu_b, lv_W, lv_b, svec, tvec, Wmuf, cmu, Wlvf, clv);
  gemm64<<<gB, 256, 0, stream>>>(g2, Wmuf, cmu, mu, N, 64, 64);
  gemm64<<<gB, 256, 0, stream>>>(g2, Wlvf, clv, lv, N, 64, 64);

  // 8. z, res_z, res_z → bf16
  reparam<<<(N * 64 + 255) / 256, 256, 0, stream>>>(mu, lv, eps, zb, N * 64);
  gemm64<<<gB, 256, 0, stream>>>(zb, res_W, res_b, rz, N, 64, 64);
  cvt_bf16<<<(N * 16 + 255) / 256, 256, 0, stream>>>(rz, rzb, N * 16);

  // 9. MFMA decoder
  decoder_mfma<<<(E + 63) / 64, 256, 0, stream>>>(ei, E, rzb, W1t, dec_b1, dec_W2, dec_b2, recon);
}

// Round 3
// 748.649 us; speedup vs baseline: 1.8504x; 1.1610x over previous
//
#include <hip/hip_runtime.h>
#include <math.h>

constexpr int DIN = 256;
constexpr int HID = 128;
constexpr int LAT = 64;

typedef short bfrag __attribute__((ext_vector_type(8)));   // 8 bf16 (4 VGPRs)
typedef float f32x4 __attribute__((ext_vector_type(4)));

__device__ __forceinline__ float4 ld4(const float* p) { return *reinterpret_cast<const float4*>(p); }
__device__ __forceinline__ void st4(float* p, float4 v) { *reinterpret_cast<float4*>(p) = v; }

__device__ __forceinline__ unsigned short f2bf(float f) {
  unsigned int u = __float_as_uint(f);
  unsigned int r = (u + 0x7FFFu + ((u >> 16) & 1u)) >> 16;  // RNE
  return (unsigned short)r;
}

// ---------------- generic f32 GEMM: C[M,N] = A[M,K] @ B[K,N] (+ crow[N]) ----------------
__global__ __launch_bounds__(256) void gemm64(const float* __restrict__ A, const float* __restrict__ B,
                                              const float* __restrict__ crow, float* __restrict__ C,
                                              int M, int N, int K) {
  __shared__ float As[32][68];
  __shared__ float Bs[32][68];
  int t = threadIdx.x;
  int m0 = blockIdx.x * 64, n0 = blockIdx.y * 64;
  int tm = t & 15, tn = t >> 4;
  float acc[4][4];
#pragma unroll
  for (int i = 0; i < 4; i++)
#pragma unroll
    for (int j = 0; j < 4; j++) acc[i][j] = 0.f;

  for (int kt = 0; kt < K; kt += 32) {
#pragma unroll
    for (int i = 0; i < 2; ++i) {
      int f4 = t + i * 256;
      int m = f4 >> 3;
      int k4 = (f4 & 7) << 2;
      int gm = m0 + m;
      float4 v = make_float4(0.f, 0.f, 0.f, 0.f);
      if (gm < M) v = ld4(A + (size_t)gm * K + kt + k4);
      As[k4 + 0][m] = v.x; As[k4 + 1][m] = v.y; As[k4 + 2][m] = v.z; As[k4 + 3][m] = v.w;
    }
#pragma unroll
    for (int i = 0; i < 2; ++i) {
      int f4 = t + i * 256;
      int k = f4 >> 4;
      int n4 = (f4 & 15) << 2;
      float4 v = ld4(B + (size_t)(kt + k) * N + n0 + n4);
      st4(&Bs[k][n4], v);
    }
    __syncthreads();
#pragma unroll
    for (int k = 0; k < 32; ++k) {
      float4 a = ld4(&As[k][tm << 2]);
      float4 b = ld4(&Bs[k][tn << 2]);
      float av[4] = {a.x, a.y, a.z, a.w};
      float bv[4] = {b.x, b.y, b.z, b.w};
#pragma unroll
      for (int i = 0; i < 4; i++)
#pragma unroll
        for (int j = 0; j < 4; j++) acc[i][j] = fmaf(av[i], bv[j], acc[i][j]);
    }
    __syncthreads();
  }
#pragma unroll
  for (int i = 0; i < 4; ++i) {
    int gm = m0 + (tm << 2) + i;
    if (gm < M) {
      int nb = n0 + (tn << 2);
      float4 v = make_float4(acc[i][0], acc[i][1], acc[i][2], acc[i][3]);
      if (crow) { v.x += crow[nb]; v.y += crow[nb + 1]; v.z += crow[nb + 2]; v.w += crow[nb + 3]; }
      st4(C + (size_t)gm * N + nb, v);
    }
  }
}

// ---------------- attention scores ----------------
__global__ __launch_bounds__(256) void attn_scores(const float* __restrict__ xp,
                                                   const float* __restrict__ att_src,
                                                   const float* __restrict__ att_dst,
                                                   float* __restrict__ a_src, float* __restrict__ a_dst, int N) {
  int wid = threadIdx.x >> 6, lane = threadIdx.x & 63;
  int n = blockIdx.x * 4 + wid;
  if (n >= N) return;
  int h = lane >> 5;
  int f4 = (lane & 31) << 2;
  float4 v = ld4(xp + (size_t)n * 256 + h * 128 + f4);
  float4 as = ld4(att_src + h * 128 + f4);
  float4 ad = ld4(att_dst + h * 128 + f4);
  float ps = v.x * as.x + v.y * as.y + v.z * as.z + v.w * as.w;
  float pd = v.x * ad.x + v.y * ad.y + v.z * ad.z + v.w * ad.w;
#pragma unroll
  for (int m = 16; m >= 1; m >>= 1) { ps += __shfl_xor(ps, m); pd += __shfl_xor(pd, m); }
  if ((lane & 31) == 0) { a_src[n * 2 + h] = ps; a_dst[n * 2 + h] = pd; }
}

// ---------------- CSR build ----------------
__global__ void deg_count(const int* __restrict__ ei, int E, int Et, int* __restrict__ deg) {
  int i = blockIdx.x * blockDim.x + threadIdx.x;
  if (i >= Et) return;
  int d = (i < E) ? ei[E + i] : (i - E);
  atomicAdd(&deg[d], 1);
}

// 3-phase device-wide exclusive scan of deg[0..N) in 256-element chunks.
__global__ __launch_bounds__(256) void bsum_kernel(const int* __restrict__ deg, int N, int* __restrict__ bsum) {
  int t = threadIdx.x;
  int i = blockIdx.x * 256 + t;
  int v = (i < N) ? deg[i] : 0;
#pragma unroll
  for (int m = 32; m >= 1; m >>= 1) v += __shfl_xor(v, m);
  __shared__ int sh[4];
  if ((t & 63) == 0) sh[t >> 6] = v;
  __syncthreads();
  if (t == 0) bsum[blockIdx.x] = sh[0] + sh[1] + sh[2] + sh[3];
}

__global__ __launch_bounds__(256) void bscan_kernel(int* __restrict__ bsum, int B) {
  // single block: exclusive scan in place (B <= 256)
  __shared__ int sh[256];
  int t = threadIdx.x;
  int v = (t < B) ? bsum[t] : 0;
  sh[t] = v;
  __syncthreads();
  for (int d = 1; d < 256; d <<= 1) {
    int x = (t >= d) ? sh[t - d] : 0;
    __syncthreads();
    sh[t] += x;
    __syncthreads();
  }
  if (t < B) bsum[t] = sh[t] - v;
}

__global__ __launch_bounds__(256) void scan_apply(const int* __restrict__ deg, const int* __restrict__ bsum, int N,
                                                  int* __restrict__ offs, int* __restrict__ cursor,
                                                  float* __restrict__ dinv) {
  int t = threadIdx.x;
  int i = blockIdx.x * 256 + t;
  int v = (i < N) ? deg[i] : 0;
  __shared__ int sh[256];
  sh[t] = v;
  __syncthreads();
  for (int d = 1; d < 256; d <<= 1) {
    int x = (t >= d) ? sh[t - d] : 0;
    __syncthreads();
    sh[t] += x;
    __syncthreads();
  }
  if (i < N) {
    int off = bsum[blockIdx.x] + sh[t] - v;
    offs[i] = off;
    cursor[i] = off;
    dinv[i] = rsqrtf((float)v);   // deg >= 1 (self-loop)
  }
}

__global__ void csr_fill(const int* __restrict__ ei, int E, int Et, int* __restrict__ cursor, int* __restrict__ csr) {
  int i = blockIdx.x * blockDim.x + threadIdx.x;
  if (i >= Et) return;
  int s, d;
  if (i < E) { s = ei[i]; d = ei[E + i]; } else { s = i - E; d = i - E; }
  int pos = atomicAdd(&cursor[d], 1);
  csr[pos] = s;
}

// ---------------- GAT softmax per dst node (wave per node) ----------------
__global__ __launch_bounds__(256) void gat_softmax(const int* __restrict__ offs, const int* __restrict__ deg,
                                                   const int* __restrict__ csr, const float* __restrict__ a_src,
                                                   const float* __restrict__ a_dst, float* __restrict__ alpha, int N) {
  int wid = threadIdx.x >> 6, lane = threadIdx.x & 63;
  int n = blockIdx.x * 4 + wid;
  if (n >= N) return;
  int off = offs[n], dg = deg[n];
  float ad0 = a_dst[n * 2], ad1 = a_dst[n * 2 + 1];
  float m0 = -1e30f, m1 = -1e30f;
  for (int k = lane; k < dg; k += 64) {
    int s = csr[off + k];
    float e0 = a_src[s * 2] + ad0; e0 = e0 >= 0.f ? e0 : 0.2f * e0;
    float e1 = a_src[s * 2 + 1] + ad1; e1 = e1 >= 0.f ? e1 : 0.2f * e1;
    m0 = fmaxf(m0, e0); m1 = fmaxf(m1, e1);
  }
#pragma unroll
  for (int m = 32; m >= 1; m >>= 1) { m0 = fmaxf(m0, __shfl_xor(m0, m)); m1 = fmaxf(m1, __shfl_xor(m1, m)); }
  float s0 = 0.f, s1 = 0.f;
  float2* al2 = (float2*)alpha;
  for (int k = lane; k < dg; k += 64) {
    int s = csr[off + k];
    float e0 = a_src[s * 2] + ad0; e0 = e0 >= 0.f ? e0 : 0.2f * e0;
    float e1 = a_src[s * 2 + 1] + ad1; e1 = e1 >= 0.f ? e1 : 0.2f * e1;
    float x0 = __expf(e0 - m0), x1 = __expf(e1 - m1);
    al2[off + k] = make_float2(x0, x1);
    s0 += x0; s1 += x1;
  }
#pragma unroll
  for (int m = 32; m >= 1; m >>= 1) { s0 += __shfl_xor(s0, m); s1 += __shfl_xor(s1, m); }
  float r0 = 1.f / s0, r1 = 1.f / s1;
  for (int k = lane; k < dg; k += 64) {
    float2 v = al2[off + k];
    al2[off + k] = make_float2(v.x * r0, v.y * r1);
  }
}

// ---------------- GAT aggregation (wave per node) ----------------
__global__ __launch_bounds__(256) void gat_aggregate(const int* __restrict__ offs, const int* __restrict__ deg,
                                                     const int* __restrict__ csr, const float* __restrict__ alpha,
                                                     const float* __restrict__ xp, const float* __restrict__ bias,
                                                     float* __restrict__ h1, int N) {
  int wid = threadIdx.x >> 6, lane = threadIdx.x & 63;
  int n = blockIdx.x * 4 + wid;
  if (n >= N) return;
  int off = offs[n], dg = deg[n];
  float4 acc = make_float4(0.f, 0.f, 0.f, 0.f);
  int f4 = lane << 2;
  bool h0 = lane < 32;
  const float2* al2 = (const float2*)alpha;
  for (int k = 0; k < dg; ++k) {
    int s = csr[off + k];
    float2 al = al2[off + k];
    float a = h0 ? al.x : al.y;
    float4 v = ld4(xp + (size_t)s * 256 + f4);
    acc.x = fmaf(v.x, a, acc.x);
    acc.y = fmaf(v.y, a, acc.y);
    acc.z = fmaf(v.z, a, acc.z);
    acc.w = fmaf(v.w, a, acc.w);
  }
  float ox = __shfl_down(acc.x, 32);
  float oy = __shfl_down(acc.y, 32);
  float oz = __shfl_down(acc.z, 32);
  float ow = __shfl_down(acc.w, 32);
  if (h0) {
    float4 b = ld4(bias + f4);
    float4 o;
    o.x = fmaxf(0.f, (acc.x + ox) * 0.5f + b.x);
    o.y = fmaxf(0.f, (acc.y + oy) * 0.5f + b.y);
    o.z = fmaxf(0.f, (acc.z + oz) * 0.5f + b.z);
    o.w = fmaxf(0.f, (acc.w + ow) * 0.5f + b.w);
    st4(h1 + (size_t)n * 128 + f4, o);
  }
}

// ---------------- BatchNorm stats ----------------
template <int C>
__global__ __launch_bounds__(256) void bn_stats(const float* __restrict__ h, int N, float* __restrict__ P,
                                                float* __restrict__ PS) {
  constexpr int R = 256 / C;
  __shared__ float sh[256], sh2[256];
  int t = threadIdx.x;
  int c = t % C, r = t / C;
  float s = 0.f, ss = 0.f;
  for (int n = blockIdx.x * R + r; n < N; n += gridDim.x * R) {
    float v = h[(size_t)n * C + c];
    s += v; ss += v * v;
  }
  sh[t] = s; sh2[t] = ss;
  __syncthreads();
  if (r == 0) {
#pragma unroll
    for (int i = 1; i < R; ++i) { s += sh[i * C + c]; ss += sh2[i * C + c]; }
    P[blockIdx.x * C + c] = s;
    PS[blockIdx.x * C + c] = ss;
  }
}

template <int C>
__global__ void bn_reduce(const float* __restrict__ P, const float* __restrict__ PS, int G, int N,
                          const float* __restrict__ g, const float* __restrict__ b,
                          float* __restrict__ svec, float* __restrict__ tvec) {
  int c = threadIdx.x;
  if (c >= C) return;
  float s = 0.f, ss = 0.f;
  for (int i = 0; i < G; ++i) { s += P[i * C + c]; ss += PS[i * C + c]; }
  float mean = s / N;
  float var = ss / N - mean * mean;
  float sc = g[c] * rsqrtf(var + 1e-5f);
  svec[c] = sc;
  tvec[c] = b[c] - mean * sc;
}

__global__ __launch_bounds__(256) void fold_gcn(const float* __restrict__ W, const float* __restrict__ svec,
                                                const float* __restrict__ tvec, float* __restrict__ Wf,
                                                float* __restrict__ cvec) {
  int t = threadIdx.x;
  for (int i = t; i < 128 * 64; i += 256) {
    int k = i >> 6;
    Wf[i] = svec[k] * W[i];
  }
  if (t < 64) {
    float c = 0.f;
    for (int k = 0; k < 128; ++k) c += tvec[k] * W[k * 64 + t];
    cvec[t] = c;
  }
}

__global__ __launch_bounds__(256) void fold_mulv(const float* __restrict__ Wmu, const float* __restrict__ mub,
                                                 const float* __restrict__ Wlv, const float* __restrict__ lvb,
                                                 const float* __restrict__ svec, const float* __restrict__ tvec,
                                                 float* __restrict__ Wmuf, float* __restrict__ cmu,
                                                 float* __restrict__ Wlvf, float* __restrict__ clv) {
  int t = threadIdx.x;
  for (int i = t; i < 4096; i += 256) {
    int k = i >> 6;
    Wmuf[i] = svec[k] * Wmu[i];
    Wlvf[i] = svec[k] * Wlv[i];
  }
  if (t < 64) {
    float cm = mub[t], cl = lvb[t];
    for (int k = 0; k < 64; ++k) { cm += tvec[k] * Wmu[k * 64 + t]; cl += tvec[k] * Wlv[k * 64 + t]; }
    cmu[t] = cm; clv[t] = cl;
  }
}

// ---------------- GCN aggregation ----------------
__global__ __launch_bounds__(256) void gcn_aggregate(const int* __restrict__ offs, const int* __restrict__ deg,
                                                     const int* __restrict__ csr, const float* __restrict__ xp2,
                                                     const float* __restrict__ dinv, const float* __restrict__ bias,
                                                     float* __restrict__ g2, int N) {
  int wid = threadIdx.x >> 6, lane = threadIdx.x & 63;
  int n = blockIdx.x * 4 + wid;
  if (n >= N) return;
  int off = offs[n], dg = deg[n];
  float acc = 0.f;
  for (int k = 0; k < dg; ++k) {
    int s = csr[off + k];
    acc = fmaf(xp2[(size_t)s * 64 + lane], dinv[s], acc);
  }
  float v = acc * dinv[n] + bias[lane];
  g2[(size_t)n * 64 + lane] = fmaxf(v, 0.f);
}

// ---------------- reparameterize ----------------
__global__ void reparam(const float* __restrict__ mu, const float* __restrict__ lv,
                        const float* __restrict__ eps, float* __restrict__ z, int total) {
  int i = blockIdx.x * blockDim.x + threadIdx.x;
  if (i >= total) return;
  z[i] = fmaf(eps[i], __expf(0.5f * lv[i]), mu[i]);
}

// ---------------- bf16 conversion of res_z ----------------
__global__ void cvt_bf16(const float* __restrict__ in, unsigned short* __restrict__ out, int n4) {
  int i = blockIdx.x * blockDim.x + threadIdx.x;
  if (i >= n4) return;
  float4 v = ((const float4*)in)[i];
  ushort4 o;
  o.x = f2bf(v.x); o.y = f2bf(v.y); o.z = f2bf(v.z); o.w = f2bf(v.w);
  ((ushort4*)out)[i] = o;
}

// ---------------- prep W1 → bf16 decoder-ready layout [4 kt][256 j][40 kp] ----------------
__global__ void prep_W1(const float* __restrict__ W1, unsigned short* __restrict__ W1t) {
  int i = blockIdx.x * blockDim.x + threadIdx.x;
  if (i >= 4 * 256 * 40) return;
  int kt = i / 10240;
  int rem = i - kt * 10240;
  int j = rem / 40;
  int kp = rem - j * 40;
  float v = (kp < 32) ? W1[(size_t)(kt * 32 + kp) * 256 + j] : 0.f;
  W1t[i] = f2bf(v);
}

// ---------------- MFMA decoder ----------------
__global__ __launch_bounds__(256) void decoder_mfma(const int* __restrict__ ei, int E,
                                                    const unsigned short* __restrict__ rzb,
                                                    const unsigned short* __restrict__ W1t,
                                                    const float* __restrict__ b1, const float* __restrict__ W2,
                                                    const float* __restrict__ b2, float* __restrict__ recon) {
  __shared__ unsigned short Als[64 * 128];   // 16 KB
  __shared__ unsigned short Bls[256 * 40];   // 20 KB
  __shared__ float red[4][64];
  int t = threadIdx.x;
  int wv = t >> 6, l = t & 63;
  int lg = l >> 4, ll = l & 15;
  int e0 = blockIdx.x * 64;

  // ---- stage A: gather e_emb rows (bf16), swizzled ----
  {
    int e = t >> 2;
    int part = (t >> 1) & 1;
    int half = t & 1;
    int eg = e0 + e;
    if (eg >= E) eg = E - 1;
    int r = (part == 0) ? ei[eg] : ei[E + eg];
    const uint4* gsrc = (const uint4*)(rzb + (size_t)r * 64 + half * 32);
    int bo0 = part * 128 + half * 64;
    int swz = (e & 7) << 4;
#pragma unroll
    for (int c = 0; c < 4; ++c) {
      uint4 v = gsrc[c];
      int bo = bo0 + c * 16;
      *(uint4*)&Als[e * 128 + ((bo ^ swz) >> 1)] = v;
    }
  }

  f32x4 acc[4][4];
#pragma unroll
  for (int a = 0; a < 4; ++a)
#pragma unroll
    for (int b = 0; b < 4; ++b) acc[a][b] = (f32x4){0.f, 0.f, 0.f, 0.f};

  for (int kt = 0; kt < 4; ++kt) {
    __syncthreads();
    {
      const uint4* gsrc = (const uint4*)(W1t + kt * 10240);
      uint4* ldst = (uint4*)Bls;
#pragma unroll
      for (int i = 0; i < 5; ++i) ldst[t + i * 256] = gsrc[t + i * 256];
    }
    __syncthreads();

    bfrag af[4];
#pragma unroll
    for (int fm = 0; fm < 4; ++fm) {
      int e = fm * 16 + ll;
      int bo = kt * 64 + lg * 16;
      af[fm] = *(const bfrag*)&Als[e * 128 + ((bo ^ ((e & 7) << 4)) >> 1)];
    }
#pragma unroll
    for (int fn = 0; fn < 4; ++fn) {
      int j = wv * 64 + fn * 16 + ll;
      bfrag bf = *(const bfrag*)&Bls[j * 40 + lg * 8];
#pragma unroll
      for (int fm = 0; fm < 4; ++fm)
        acc[fm][fn] = __builtin_amdgcn_mfma_f32_16x16x32_bf16(af[fm], bf, acc[fm][fn], 0, 0, 0);
    }
  }

  float bj[4], wj[4];
#pragma unroll
  for (int fn = 0; fn < 4; ++fn) {
    int j = wv * 64 + fn * 16 + ll;
    bj[fn] = b1[j];
    wj[fn] = W2[j];
  }
#pragma unroll
  for (int fm = 0; fm < 4; ++fm) {
    float pr[4] = {0.f, 0.f, 0.f, 0.f};
#pragma unroll
    for (int fn = 0; fn < 4; ++fn) {
#pragma unroll
      for (int r = 0; r < 4; ++r)
        pr[r] = fmaf(fmaxf(acc[fm][fn][r] + bj[fn], 0.f), wj[fn], pr[r]);
    }
#pragma unroll
    for (int m = 8; m >= 1; m >>= 1) {
#pragma unroll
      for (int r = 0; r < 4; ++r) pr[r] += __shfl_xor(pr[r], m);
    }
    if (ll == 0) {
#pragma unroll
      for (int r = 0; r < 4; ++r) red[wv][fm * 16 + lg * 4 + r] = pr[r];
    }
  }
  __syncthreads();
  if (t < 64) {
    int eg = e0 + t;
    if (eg < E) recon[eg] = red[0][t] + red[1][t] + red[2][t] + red[3][t] + b2[0];
  }
}

extern "C" void kernel_launch(void* const* d_in, const int* in_sizes, int n_in,
                              void* d_out, int out_size, void* d_ws, size_t ws_size,
                              hipStream_t stream) {
  const float* x = (const float*)d_in[0];
  const int* ei = (const int*)d_in[1];
  const float* gat_W = (const float*)d_in[2];
  const float* att_src = (const float*)d_in[3];
  const float* att_dst = (const float*)d_in[4];
  const float* gat_bias = (const float*)d_in[5];
  const float* bn1_g = (const float*)d_in[6];
  const float* bn1_b = (const float*)d_in[7];
  const float* gcn_W = (const float*)d_in[8];
  const float* gcn_bias = (const float*)d_in[9];
  const float* bn2_g = (const float*)d_in[10];
  const float* bn2_b = (const float*)d_in[11];
  const float* mu_W = (const float*)d_in[12];
  const float* mu_b = (const float*)d_in[13];
  const float* lv_W = (const float*)d_in[14];
  const float* lv_b = (const float*)d_in[15];
  const float* res_W = (const float*)d_in[16];
  const float* res_b = (const float*)d_in[17];
  const float* dec_W1 = (const float*)d_in[18];
  const float* dec_b1 = (const float*)d_in[19];
  const float* dec_W2 = (const float*)d_in[20];
  const float* dec_b2 = (const float*)d_in[21];
  const float* eps = (const float*)d_in[22];

  int N = in_sizes[0] / DIN;   // 50000
  int E = in_sizes[1] / 2;     // 800000
  int Et = E + N;
  int NB = (N + 255) / 256;    // scan chunks (<= 256)

  float* ws = (float*)d_ws;
  size_t off = 0;
  float* xp = ws; off += (size_t)N * 256;
  float* xp2 = xp;
  float* g2 = xp + (size_t)N * 64;
  float* zb = xp + (size_t)N * 128;
  float* rz = xp + (size_t)N * 192;
  unsigned short* rzb = (unsigned short*)zb;
  float* h1 = ws + off; off += (size_t)N * 128;
  float* a_src = ws + off; off += (size_t)2 * N;
  float* a_dst = ws + off; off += (size_t)2 * N;
  float* alpha = ws + off; off += (size_t)Et * 2;
  float* dinv = ws + off; off += N;
  float* P = ws + off; off += 128 * 128;
  float* PS = ws + off; off += 128 * 128;
  float* svec = ws + off; off += 128;
  float* tvec = ws + off; off += 128;
  float* W2f = ws + off; off += 128 * 64;
  float* c2 = ws + off; off += 64;
  float* Wmuf = ws + off; off += 64 * 64;
  float* cmu = ws + off; off += 64;
  float* Wlvf = ws + off; off += 64 * 64;
  float* clv = ws + off; off += 64;
  unsigned short* W1t = (unsigned short*)(ws + off); off += 20480;
  int* deg = (int*)(ws + off); off += N;
  int* offs = (int*)(ws + off); off += N;
  int* cursor = (int*)(ws + off); off += N;
  int* bsum = (int*)(ws + off); off += 256;
  int* csr = (int*)(ws + off); off += Et;

  float* recon = (float*)d_out;
  float* mu = recon + E;
  float* lv = mu + (size_t)N * LAT;

  // 0. prep W1 (independent, do early)
  prep_W1<<<(4 * 256 * 40 + 255) / 256, 256, 0, stream>>>(dec_W1, W1t);

  // 1. xp = x @ gat_W
  dim3 gA((N + 63) / 64, DIN / 64);
  gemm64<<<gA, 256, 0, stream>>>(x, gat_W, nullptr, xp, N, DIN, DIN);

  // 2. attention scores
  attn_scores<<<(N + 3) / 4, 256, 0, stream>>>(xp, att_src, att_dst, a_src, a_dst, N);

  // 3. CSR build (parallel 3-phase scan)
  hipMemsetAsync(deg, 0, (size_t)N * sizeof(int), stream);
  deg_count<<<(Et + 255) / 256, 256, 0, stream>>>(ei, E, Et, deg);
  bsum_kernel<<<NB, 256, 0, stream>>>(deg, N, bsum);
  bscan_kernel<<<1, 256, 0, stream>>>(bsum, NB);
  scan_apply<<<NB, 256, 0, stream>>>(deg, bsum, N, offs, cursor, dinv);
  csr_fill<<<(Et + 255) / 256, 256, 0, stream>>>(ei, E, Et, cursor, csr);

  // 4. GAT softmax + aggregation
  gat_softmax<<<(N + 3) / 4, 256, 0, stream>>>(offs, deg, csr, a_src, a_dst, alpha, N);
  gat_aggregate<<<(N + 3) / 4, 256, 0, stream>>>(offs, deg, csr, alpha, xp, gat_bias, h1, N);

  // 5. BN1 folded into GCN weights
  bn_stats<128><<<128, 256, 0, stream>>>(h1, N, P, PS);
  bn_reduce<128><<<1, 128, 0, stream>>>(P, PS, 128, N, bn1_g, bn1_b, svec, tvec);
  fold_gcn<<<1, 256, 0, stream>>>(gcn_W, svec, tvec, W2f, c2);
  dim3 gB((N + 63) / 64, 1);
  gemm64<<<gB, 256, 0, stream>>>(h1, W2f, c2, xp2, N, 64, 128);

  // 6. GCN aggregation
  gcn_aggregate<<<(N + 3) / 4, 256, 0, stream>>>(offs, deg, csr, xp2, dinv, gcn_bias, g2, N);

  // 7. BN2 folded into mu/lv
  bn_stats<64><<<128, 256, 0, stream>>>(g2, N, P, PS);
  bn_reduce<64><<<1, 64, 0, stream>>>(P, PS, 128, N, bn2_g, bn2_b, svec, tvec);
  fold_mulv<<<1, 256, 0, stream>>>(mu_W, mu_b, lv_W, lv_b, svec, tvec, Wmuf, cmu, Wlvf, clv);
  gemm64<<<gB, 256, 0, stream>>>(g2, Wmuf, cmu, mu, N, 64, 64);
  gemm64<<<gB, 256, 0, stream>>>(g2, Wlvf, clv, lv, N, 64, 64);

  // 8. z, res_z, res_z → bf16
  reparam<<<(N * 64 + 255) / 256, 256, 0, stream>>>(mu, lv, eps, zb, N * 64);
  gemm64<<<gB, 256, 0, stream>>>(zb, res_W, res_b, rz, N, 64, 64);
  cvt_bf16<<<(N * 16 + 255) / 256, 256, 0, stream>>>(rz, rzb, N * 16);

  // 9. MFMA decoder
  decoder_mfma<<<(E + 63) / 64, 256, 0, stream>>>(ei, E, rzb, W1t, dec_b1, dec_W2, dec_b2, recon);
}

// Round 4
// 736.634 us; speedup vs baseline: 1.8806x; 1.0163x over previous
//
#include <hip/hip_runtime.h>
#include <math.h>

constexpr int DIN = 256;
constexpr int HID = 128;
constexpr int LAT = 64;

typedef short bfrag __attribute__((ext_vector_type(8)));   // 8 bf16 (4 VGPRs)
typedef float f32x4 __attribute__((ext_vector_type(4)));

__device__ __forceinline__ float4 ld4(const float* p) { return *reinterpret_cast<const float4*>(p); }
__device__ __forceinline__ void st4(float* p, float4 v) { *reinterpret_cast<float4*>(p) = v; }

__device__ __forceinline__ unsigned short f2bf(float f) {
  unsigned int u = __float_as_uint(f);
  unsigned int r = (u + 0x7FFFu + ((u >> 16) & 1u)) >> 16;  // RNE
  return (unsigned short)r;
}

__device__ __forceinline__ float bf2f(unsigned short u) {
  return __uint_as_float(((unsigned int)u) << 16);
}

// ---------------- generic f32 GEMM: C[M,N] = A[M,K] @ B[K,N] (+ crow[N]) ----------------
__global__ __launch_bounds__(256) void gemm64(const float* __restrict__ A, const float* __restrict__ B,
                                              const float* __restrict__ crow, float* __restrict__ C,
                                              int M, int N, int K) {
  __shared__ float As[32][68];
  __shared__ float Bs[32][68];
  int t = threadIdx.x;
  int m0 = blockIdx.x * 64, n0 = blockIdx.y * 64;
  int tm = t & 15, tn = t >> 4;
  float acc[4][4];
#pragma unroll
  for (int i = 0; i < 4; i++)
#pragma unroll
    for (int j = 0; j < 4; j++) acc[i][j] = 0.f;

  for (int kt = 0; kt < K; kt += 32) {
#pragma unroll
    for (int i = 0; i < 2; ++i) {
      int f4 = t + i * 256;
      int m = f4 >> 3;
      int k4 = (f4 & 7) << 2;
      int gm = m0 + m;
      float4 v = make_float4(0.f, 0.f, 0.f, 0.f);
      if (gm < M) v = ld4(A + (size_t)gm * K + kt + k4);
      As[k4 + 0][m] = v.x; As[k4 + 1][m] = v.y; As[k4 + 2][m] = v.z; As[k4 + 3][m] = v.w;
    }
#pragma unroll
    for (int i = 0; i < 2; ++i) {
      int f4 = t + i * 256;
      int k = f4 >> 4;
      int n4 = (f4 & 15) << 2;
      float4 v = ld4(B + (size_t)(kt + k) * N + n0 + n4);
      st4(&Bs[k][n4], v);
    }
    __syncthreads();
#pragma unroll
    for (int k = 0; k < 32; ++k) {
      float4 a = ld4(&As[k][tm << 2]);
      float4 b = ld4(&Bs[k][tn << 2]);
      float av[4] = {a.x, a.y, a.z, a.w};
      float bv[4] = {b.x, b.y, b.z, b.w};
#pragma unroll
      for (int i = 0; i < 4; i++)
#pragma unroll
        for (int j = 0; j < 4; j++) acc[i][j] = fmaf(av[i], bv[j], acc[i][j]);
    }
    __syncthreads();
  }
#pragma unroll
  for (int i = 0; i < 4; ++i) {
    int gm = m0 + (tm << 2) + i;
    if (gm < M) {
      int nb = n0 + (tn << 2);
      float4 v = make_float4(acc[i][0], acc[i][1], acc[i][2], acc[i][3]);
      if (crow) { v.x += crow[nb]; v.y += crow[nb + 1]; v.z += crow[nb + 2]; v.w += crow[nb + 3]; }
      st4(C + (size_t)gm * N + nb, v);
    }
  }
}

// ---------------- attention scores ----------------
__global__ __launch_bounds__(256) void attn_scores(const float* __restrict__ xp,
                                                   const float* __restrict__ att_src,
                                                   const float* __restrict__ att_dst,
                                                   float* __restrict__ a_src, float* __restrict__ a_dst, int N) {
  int wid = threadIdx.x >> 6, lane = threadIdx.x & 63;
  int n = blockIdx.x * 4 + wid;
  if (n >= N) return;
  int h = lane >> 5;
  int f4 = (lane & 31) << 2;
  float4 v = ld4(xp + (size_t)n * 256 + h * 128 + f4);
  float4 as = ld4(att_src + h * 128 + f4);
  float4 ad = ld4(att_dst + h * 128 + f4);
  float ps = v.x * as.x + v.y * as.y + v.z * as.z + v.w * as.w;
  float pd = v.x * ad.x + v.y * ad.y + v.z * ad.z + v.w * ad.w;
#pragma unroll
  for (int m = 16; m >= 1; m >>= 1) { ps += __shfl_xor(ps, m); pd += __shfl_xor(pd, m); }
  if ((lane & 31) == 0) { a_src[n * 2 + h] = ps; a_dst[n * 2 + h] = pd; }
}

// ---------------- in-place f32 row -> bf16 half-row convert (wave per row) ----------------
// Row n: 256 f32 (1024 B) -> 256 bf16 packed into the row's first 512 B.
// All loads complete before the barrier; stores after -> no overlap race.
__global__ __launch_bounds__(256) void cvt_rows_inplace(float* __restrict__ xp, int N) {
  int wid = threadIdx.x >> 6, lane = threadIdx.x & 63;
  int n = blockIdx.x * 4 + wid;
  float4 v = make_float4(0.f, 0.f, 0.f, 0.f);
  float* row = xp + (size_t)n * 256;
  if (n < N) v = ld4(row + (lane << 2));
  __syncthreads();
  if (n < N) {
    ushort4 o;
    o.x = f2bf(v.x); o.y = f2bf(v.y); o.z = f2bf(v.z); o.w = f2bf(v.w);
    ((ushort4*)row)[lane] = o;
  }
}

// ---------------- CSR build ----------------
__global__ void deg_count(const int* __restrict__ ei, int E, int Et, int* __restrict__ deg) {
  int i = blockIdx.x * blockDim.x + threadIdx.x;
  if (i >= Et) return;
  int d = (i < E) ? ei[E + i] : (i - E);
  atomicAdd(&deg[d], 1);
}

// 3-phase device-wide exclusive scan of deg[0..N) in 256-element chunks.
__global__ __launch_bounds__(256) void bsum_kernel(const int* __restrict__ deg, int N, int* __restrict__ bsum) {
  int t = threadIdx.x;
  int i = blockIdx.x * 256 + t;
  int v = (i < N) ? deg[i] : 0;
#pragma unroll
  for (int m = 32; m >= 1; m >>= 1) v += __shfl_xor(v, m);
  __shared__ int sh[4];
  if ((t & 63) == 0) sh[t >> 6] = v;
  __syncthreads();
  if (t == 0) bsum[blockIdx.x] = sh[0] + sh[1] + sh[2] + sh[3];
}

__global__ __launch_bounds__(256) void bscan_kernel(int* __restrict__ bsum, int B) {
  __shared__ int sh[256];
  int t = threadIdx.x;
  int v = (t < B) ? bsum[t] : 0;
  sh[t] = v;
  __syncthreads();
  for (int d = 1; d < 256; d <<= 1) {
    int x = (t >= d) ? sh[t - d] : 0;
    __syncthreads();
    sh[t] += x;
    __syncthreads();
  }
  if (t < B) bsum[t] = sh[t] - v;
}

__global__ __launch_bounds__(256) void scan_apply(const int* __restrict__ deg, const int* __restrict__ bsum, int N,
                                                  int* __restrict__ offs, int* __restrict__ cursor,
                                                  float* __restrict__ dinv) {
  int t = threadIdx.x;
  int i = blockIdx.x * 256 + t;
  int v = (i < N) ? deg[i] : 0;
  __shared__ int sh[256];
  sh[t] = v;
  __syncthreads();
  for (int d = 1; d < 256; d <<= 1) {
    int x = (t >= d) ? sh[t - d] : 0;
    __syncthreads();
    sh[t] += x;
    __syncthreads();
  }
  if (i < N) {
    int off = bsum[blockIdx.x] + sh[t] - v;
    offs[i] = off;
    cursor[i] = off;
    dinv[i] = rsqrtf((float)v);   // deg >= 1 (self-loop)
  }
}

__global__ void csr_fill(const int* __restrict__ ei, int E, int Et, int* __restrict__ cursor, int* __restrict__ csr) {
  int i = blockIdx.x * blockDim.x + threadIdx.x;
  if (i >= Et) return;
  int s, d;
  if (i < E) { s = ei[i]; d = ei[E + i]; } else { s = i - E; d = i - E; }
  int pos = atomicAdd(&cursor[d], 1);
  csr[pos] = s;
}

// ---------------- GAT softmax per dst node (wave per node) ----------------
__global__ __launch_bounds__(256) void gat_softmax(const int* __restrict__ offs, const int* __restrict__ deg,
                                                   const int* __restrict__ csr, const float* __restrict__ a_src,
                                                   const float* __restrict__ a_dst, float* __restrict__ alpha, int N) {
  int wid = threadIdx.x >> 6, lane = threadIdx.x & 63;
  int n = blockIdx.x * 4 + wid;
  if (n >= N) return;
  int off = offs[n], dg = deg[n];
  float ad0 = a_dst[n * 2], ad1 = a_dst[n * 2 + 1];
  float m0 = -1e30f, m1 = -1e30f;
  for (int k = lane; k < dg; k += 64) {
    int s = csr[off + k];
    float e0 = a_src[s * 2] + ad0; e0 = e0 >= 0.f ? e0 : 0.2f * e0;
    float e1 = a_src[s * 2 + 1] + ad1; e1 = e1 >= 0.f ? e1 : 0.2f * e1;
    m0 = fmaxf(m0, e0); m1 = fmaxf(m1, e1);
  }
#pragma unroll
  for (int m = 32; m >= 1; m >>= 1) { m0 = fmaxf(m0, __shfl_xor(m0, m)); m1 = fmaxf(m1, __shfl_xor(m1, m)); }
  float s0 = 0.f, s1 = 0.f;
  float2* al2 = (float2*)alpha;
  for (int k = lane; k < dg; k += 64) {
    int s = csr[off + k];
    float e0 = a_src[s * 2] + ad0; e0 = e0 >= 0.f ? e0 : 0.2f * e0;
    float e1 = a_src[s * 2 + 1] + ad1; e1 = e1 >= 0.f ? e1 : 0.2f * e1;
    float x0 = __expf(e0 - m0), x1 = __expf(e1 - m1);
    al2[off + k] = make_float2(x0, x1);
    s0 += x0; s1 += x1;
  }
#pragma unroll
  for (int m = 32; m >= 1; m >>= 1) { s0 += __shfl_xor(s0, m); s1 += __shfl_xor(s1, m); }
  float r0 = 1.f / s0, r1 = 1.f / s1;
  for (int k = lane; k < dg; k += 64) {
    float2 v = al2[off + k];
    al2[off + k] = make_float2(v.x * r0, v.y * r1);
  }
}

// ---------------- GAT aggregation, bf16 gather (wave per node) ----------------
// xpb row n lives at float-slot n*256 (ushort index n*512), 256 bf16 in 512 B.
__global__ __launch_bounds__(256) void gat_aggregate_bf(const int* __restrict__ offs, const int* __restrict__ deg,
                                                        const int* __restrict__ csr, const float* __restrict__ alpha,
                                                        const unsigned short* __restrict__ xpb,
                                                        const float* __restrict__ bias,
                                                        float* __restrict__ h1, int N) {
  int wid = threadIdx.x >> 6, lane = threadIdx.x & 63;
  int n = blockIdx.x * 4 + wid;
  if (n >= N) return;
  int off = offs[n], dg = deg[n];
  float4 acc = make_float4(0.f, 0.f, 0.f, 0.f);
  int f4 = lane << 2;
  bool h0 = lane < 32;
  const float2* al2 = (const float2*)alpha;
  for (int k = 0; k < dg; ++k) {
    int s = csr[off + k];
    float2 al = al2[off + k];
    float a = h0 ? al.x : al.y;
    ushort4 u = ((const ushort4*)(xpb + (size_t)s * 512))[lane];
    acc.x = fmaf(bf2f(u.x), a, acc.x);
    acc.y = fmaf(bf2f(u.y), a, acc.y);
    acc.z = fmaf(bf2f(u.z), a, acc.z);
    acc.w = fmaf(bf2f(u.w), a, acc.w);
  }
  float ox = __shfl_down(acc.x, 32);
  float oy = __shfl_down(acc.y, 32);
  float oz = __shfl_down(acc.z, 32);
  float ow = __shfl_down(acc.w, 32);
  if (h0) {
    float4 b = ld4(bias + f4);
    float4 o;
    o.x = fmaxf(0.f, (acc.x + ox) * 0.5f + b.x);
    o.y = fmaxf(0.f, (acc.y + oy) * 0.5f + b.y);
    o.z = fmaxf(0.f, (acc.z + oz) * 0.5f + b.z);
    o.w = fmaxf(0.f, (acc.w + ow) * 0.5f + b.w);
    st4(h1 + (size_t)n * 128 + f4, o);
  }
}

// ---------------- BatchNorm stats ----------------
template <int C>
__global__ __launch_bounds__(256) void bn_stats(const float* __restrict__ h, int N, float* __restrict__ P,
                                                float* __restrict__ PS) {
  constexpr int R = 256 / C;
  __shared__ float sh[256], sh2[256];
  int t = threadIdx.x;
  int c = t % C, r = t / C;
  float s = 0.f, ss = 0.f;
  for (int n = blockIdx.x * R + r; n < N; n += gridDim.x * R) {
    float v = h[(size_t)n * C + c];
    s += v; ss += v * v;
  }
  sh[t] = s; sh2[t] = ss;
  __syncthreads();
  if (r == 0) {
#pragma unroll
    for (int i = 1; i < R; ++i) { s += sh[i * C + c]; ss += sh2[i * C + c]; }
    P[blockIdx.x * C + c] = s;
    PS[blockIdx.x * C + c] = ss;
  }
}

template <int C>
__global__ void bn_reduce(const float* __restrict__ P, const float* __restrict__ PS, int G, int N,
                          const float* __restrict__ g, const float* __restrict__ b,
                          float* __restrict__ svec, float* __restrict__ tvec) {
  int c = threadIdx.x;
  if (c >= C) return;
  float s = 0.f, ss = 0.f;
  for (int i = 0; i < G; ++i) { s += P[i * C + c]; ss += PS[i * C + c]; }
  float mean = s / N;
  float var = ss / N - mean * mean;
  float sc = g[c] * rsqrtf(var + 1e-5f);
  svec[c] = sc;
  tvec[c] = b[c] - mean * sc;
}

__global__ __launch_bounds__(256) void fold_gcn(const float* __restrict__ W, const float* __restrict__ svec,
                                                const float* __restrict__ tvec, float* __restrict__ Wf,
                                                float* __restrict__ cvec) {
  int t = threadIdx.x;
  for (int i = t; i < 128 * 64; i += 256) {
    int k = i >> 6;
    Wf[i] = svec[k] * W[i];
  }
  if (t < 64) {
    float c = 0.f;
    for (int k = 0; k < 128; ++k) c += tvec[k] * W[k * 64 + t];
    cvec[t] = c;
  }
}

__global__ __launch_bounds__(256) void fold_mulv(const float* __restrict__ Wmu, const float* __restrict__ mub,
                                                 const float* __restrict__ Wlv, const float* __restrict__ lvb,
                                                 const float* __restrict__ svec, const float* __restrict__ tvec,
                                                 float* __restrict__ Wmuf, float* __restrict__ cmu,
                                                 float* __restrict__ Wlvf, float* __restrict__ clv) {
  int t = threadIdx.x;
  for (int i = t; i < 4096; i += 256) {
    int k = i >> 6;
    Wmuf[i] = svec[k] * Wmu[i];
    Wlvf[i] = svec[k] * Wlv[i];
  }
  if (t < 64) {
    float cm = mub[t], cl = lvb[t];
    for (int k = 0; k < 64; ++k) { cm += tvec[k] * Wmu[k * 64 + t]; cl += tvec[k] * Wlv[k * 64 + t]; }
    cmu[t] = cm; clv[t] = cl;
  }
}

// ---------------- GCN aggregation ----------------
__global__ __launch_bounds__(256) void gcn_aggregate(const int* __restrict__ offs, const int* __restrict__ deg,
                                                     const int* __restrict__ csr, const float* __restrict__ xp2,
                                                     const float* __restrict__ dinv, const float* __restrict__ bias,
                                                     float* __restrict__ g2, int N) {
  int wid = threadIdx.x >> 6, lane = threadIdx.x & 63;
  int n = blockIdx.x * 4 + wid;
  if (n >= N) return;
  int off = offs[n], dg = deg[n];
  float acc = 0.f;
  for (int k = 0; k < dg; ++k) {
    int s = csr[off + k];
    acc = fmaf(xp2[(size_t)s * 64 + lane], dinv[s], acc);
  }
  float v = acc * dinv[n] + bias[lane];
  g2[(size_t)n * 64 + lane] = fmaxf(v, 0.f);
}

// ---------------- reparameterize ----------------
__global__ void reparam(const float* __restrict__ mu, const float* __restrict__ lv,
                        const float* __restrict__ eps, float* __restrict__ z, int total) {
  int i = blockIdx.x * blockDim.x + threadIdx.x;
  if (i >= total) return;
  z[i] = fmaf(eps[i], __expf(0.5f * lv[i]), mu[i]);
}

// ---------------- bf16 conversion of res_z ----------------
__global__ void cvt_bf16(const float* __restrict__ in, unsigned short* __restrict__ out, int n4) {
  int i = blockIdx.x * blockDim.x + threadIdx.x;
  if (i >= n4) return;
  float4 v = ((const float4*)in)[i];
  ushort4 o;
  o.x = f2bf(v.x); o.y = f2bf(v.y); o.z = f2bf(v.z); o.w = f2bf(v.w);
  ((ushort4*)out)[i] = o;
}

// ---------------- prep W1 → bf16 decoder-ready layout [4 kt][256 j][40 kp] ----------------
__global__ void prep_W1(const float* __restrict__ W1, unsigned short* __restrict__ W1t) {
  int i = blockIdx.x * blockDim.x + threadIdx.x;
  if (i >= 4 * 256 * 40) return;
  int kt = i / 10240;
  int rem = i - kt * 10240;
  int j = rem / 40;
  int kp = rem - j * 40;
  float v = (kp < 32) ? W1[(size_t)(kt * 32 + kp) * 256 + j] : 0.f;
  W1t[i] = f2bf(v);
}

// ---------------- MFMA decoder ----------------
__global__ __launch_bounds__(256) void decoder_mfma(const int* __restrict__ ei, int E,
                                                    const unsigned short* __restrict__ rzb,
                                                    const unsigned short* __restrict__ W1t,
                                                    const float* __restrict__ b1, const float* __restrict__ W2,
                                                    const float* __restrict__ b2, float* __restrict__ recon) {
  __shared__ unsigned short Als[64 * 128];   // 16 KB
  __shared__ unsigned short Bls[256 * 40];   // 20 KB
  __shared__ float red[4][64];
  int t = threadIdx.x;
  int wv = t >> 6, l = t & 63;
  int lg = l >> 4, ll = l & 15;
  int e0 = blockIdx.x * 64;

  // ---- stage A: gather e_emb rows (bf16), swizzled ----
  {
    int e = t >> 2;
    int part = (t >> 1) & 1;
    int half = t & 1;
    int eg = e0 + e;
    if (eg >= E) eg = E - 1;
    int r = (part == 0) ? ei[eg] : ei[E + eg];
    const uint4* gsrc = (const uint4*)(rzb + (size_t)r * 64 + half * 32);
    int bo0 = part * 128 + half * 64;
    int swz = (e & 7) << 4;
#pragma unroll
    for (int c = 0; c < 4; ++c) {
      uint4 v = gsrc[c];
      int bo = bo0 + c * 16;
      *(uint4*)&Als[e * 128 + ((bo ^ swz) >> 1)] = v;
    }
  }

  f32x4 acc[4][4];
#pragma unroll
  for (int a = 0; a < 4; ++a)
#pragma unroll
    for (int b = 0; b < 4; ++b) acc[a][b] = (f32x4){0.f, 0.f, 0.f, 0.f};

  for (int kt = 0; kt < 4; ++kt) {
    __syncthreads();
    {
      const uint4* gsrc = (const uint4*)(W1t + kt * 10240);
      uint4* ldst = (uint4*)Bls;
#pragma unroll
      for (int i = 0; i < 5; ++i) ldst[t + i * 256] = gsrc[t + i * 256];
    }
    __syncthreads();

    bfrag af[4];
#pragma unroll
    for (int fm = 0; fm < 4; ++fm) {
      int e = fm * 16 + ll;
      int bo = kt * 64 + lg * 16;
      af[fm] = *(const bfrag*)&Als[e * 128 + ((bo ^ ((e & 7) << 4)) >> 1)];
    }
#pragma unroll
    for (int fn = 0; fn < 4; ++fn) {
      int j = wv * 64 + fn * 16 + ll;
      bfrag bf = *(const bfrag*)&Bls[j * 40 + lg * 8];
#pragma unroll
      for (int fm = 0; fm < 4; ++fm)
        acc[fm][fn] = __builtin_amdgcn_mfma_f32_16x16x32_bf16(af[fm], bf, acc[fm][fn], 0, 0, 0);
    }
  }

  float bj[4], wj[4];
#pragma unroll
  for (int fn = 0; fn < 4; ++fn) {
    int j = wv * 64 + fn * 16 + ll;
    bj[fn] = b1[j];
    wj[fn] = W2[j];
  }
#pragma unroll
  for (int fm = 0; fm < 4; ++fm) {
    float pr[4] = {0.f, 0.f, 0.f, 0.f};
#pragma unroll
    for (int fn = 0; fn < 4; ++fn) {
#pragma unroll
      for (int r = 0; r < 4; ++r)
        pr[r] = fmaf(fmaxf(acc[fm][fn][r] + bj[fn], 0.f), wj[fn], pr[r]);
    }
#pragma unroll
    for (int m = 8; m >= 1; m >>= 1) {
#pragma unroll
      for (int r = 0; r < 4; ++r) pr[r] += __shfl_xor(pr[r], m);
    }
    if (ll == 0) {
#pragma unroll
      for (int r = 0; r < 4; ++r) red[wv][fm * 16 + lg * 4 + r] = pr[r];
    }
  }
  __syncthreads();
  if (t < 64) {
    int eg = e0 + t;
    if (eg < E) recon[eg] = red[0][t] + red[1][t] + red[2][t] + red[3][t] + b2[0];
  }
}

extern "C" void kernel_launch(void* const* d_in, const int* in_sizes, int n_in,
                              void* d_out, int out_size, void* d_ws, size_t ws_size,
                              hipStream_t stream) {
  const float* x = (const float*)d_in[0];
  const int* ei = (const int*)d_in[1];
  const float* gat_W = (const float*)d_in[2];
  const float* att_src = (const float*)d_in[3];
  const float* att_dst = (const float*)d_in[4];
  const float* gat_bias = (const float*)d_in[5];
  const float* bn1_g = (const float*)d_in[6];
  const float* bn1_b = (const float*)d_in[7];
  const float* gcn_W = (const float*)d_in[8];
  const float* gcn_bias = (const float*)d_in[9];
  const float* bn2_g = (const float*)d_in[10];
  const float* bn2_b = (const float*)d_in[11];
  const float* mu_W = (const float*)d_in[12];
  const float* mu_b = (const float*)d_in[13];
  const float* lv_W = (const float*)d_in[14];
  const float* lv_b = (const float*)d_in[15];
  const float* res_W = (const float*)d_in[16];
  const float* res_b = (const float*)d_in[17];
  const float* dec_W1 = (const float*)d_in[18];
  const float* dec_b1 = (const float*)d_in[19];
  const float* dec_W2 = (const float*)d_in[20];
  const float* dec_b2 = (const float*)d_in[21];
  const float* eps = (const float*)d_in[22];

  int N = in_sizes[0] / DIN;   // 50000
  int E = in_sizes[1] / 2;     // 800000
  int Et = E + N;
  int NB = (N + 255) / 256;    // scan chunks (<= 256)

  float* ws = (float*)d_ws;
  size_t off = 0;
  float* xp = ws; off += (size_t)N * 256;
  unsigned short* xpb = (unsigned short*)xp;   // bf16 rows in place, stride 512 ushorts
  float* xp2 = xp;
  float* g2 = xp + (size_t)N * 64;
  float* zb = xp + (size_t)N * 128;
  float* rz = xp + (size_t)N * 192;
  unsigned short* rzb = (unsigned short*)zb;
  float* h1 = ws + off; off += (size_t)N * 128;
  float* a_src = ws + off; off += (size_t)2 * N;
  float* a_dst = ws + off; off += (size_t)2 * N;
  float* alpha = ws + off; off += (size_t)Et * 2;
  float* dinv = ws + off; off += N;
  float* P = ws + off; off += 128 * 128;
  float* PS = ws + off; off += 128 * 128;
  float* svec = ws + off; off += 128;
  float* tvec = ws + off; off += 128;
  float* W2f = ws + off; off += 128 * 64;
  float* c2 = ws + off; off += 64;
  float* Wmuf = ws + off; off += 64 * 64;
  float* cmu = ws + off; off += 64;
  float* Wlvf = ws + off; off += 64 * 64;
  float* clv = ws + off; off += 64;
  unsigned short* W1t = (unsigned short*)(ws + off); off += 20480;
  int* deg = (int*)(ws + off); off += N;
  int* offs = (int*)(ws + off); off += N;
  int* cursor = (int*)(ws + off); off += N;
  int* bsum = (int*)(ws + off); off += 256;
  int* csr = (int*)(ws + off); off += Et;

  float* recon = (float*)d_out;
  float* mu = recon + E;
  float* lv = mu + (size_t)N * LAT;

  // 0. prep W1 (independent, do early)
  prep_W1<<<(4 * 256 * 40 + 255) / 256, 256, 0, stream>>>(dec_W1, W1t);

  // 1. xp = x @ gat_W
  dim3 gA((N + 63) / 64, DIN / 64);
  gemm64<<<gA, 256, 0, stream>>>(x, gat_W, nullptr, xp, N, DIN, DIN);

  // 2. attention scores (last f32-xp consumer)
  attn_scores<<<(N + 3) / 4, 256, 0, stream>>>(xp, att_src, att_dst, a_src, a_dst, N);

  // 2b. convert xp rows to bf16 in place (halves the gather bytes)
  cvt_rows_inplace<<<(N + 3) / 4, 256, 0, stream>>>(xp, N);

  // 3. CSR build (parallel 3-phase scan)
  hipMemsetAsync(deg, 0, (size_t)N * sizeof(int), stream);
  deg_count<<<(Et + 255) / 256, 256, 0, stream>>>(ei, E, Et, deg);
  bsum_kernel<<<NB, 256, 0, stream>>>(deg, N, bsum);
  bscan_kernel<<<1, 256, 0, stream>>>(bsum, NB);
  scan_apply<<<NB, 256, 0, stream>>>(deg, bsum, N, offs, cursor, dinv);
  csr_fill<<<(Et + 255) / 256, 256, 0, stream>>>(ei, E, Et, cursor, csr);

  // 4. GAT softmax + aggregation (bf16 gather)
  gat_softmax<<<(N + 3) / 4, 256, 0, stream>>>(offs, deg, csr, a_src, a_dst, alpha, N);
  gat_aggregate_bf<<<(N + 3) / 4, 256, 0, stream>>>(offs, deg, csr, alpha, xpb, gat_bias, h1, N);

  // 5. BN1 folded into GCN weights
  bn_stats<128><<<128, 256, 0, stream>>>(h1, N, P, PS);
  bn_reduce<128><<<1, 128, 0, stream>>>(P, PS, 128, N, bn1_g, bn1_b, svec, tvec);
  fold_gcn<<<1, 256, 0, stream>>>(gcn_W, svec, tvec, W2f, c2);
  dim3 gB((N + 63) / 64, 1);
  gemm64<<<gB, 256, 0, stream>>>(h1, W2f, c2, xp2, N, 64, 128);

  // 6. GCN aggregation
  gcn_aggregate<<<(N + 3) / 4, 256, 0, stream>>>(offs, deg, csr, xp2, dinv, gcn_bias, g2, N);

  // 7. BN2 folded into mu/lv
  bn_stats<64><<<128, 256, 0, stream>>>(g2, N, P, PS);
  bn_reduce<64><<<1, 64, 0, stream>>>(P, PS, 128, N, bn2_g, bn2_b, svec, tvec);
  fold_mulv<<<1, 256, 0, stream>>>(mu_W, mu_b, lv_W, lv_b, svec, tvec, Wmuf, cmu, Wlvf, clv);
  gemm64<<<gB, 256, 0, stream>>>(g2, Wmuf, cmu, mu, N, 64, 64);
  gemm64<<<gB, 256, 0, stream>>>(g2, Wlvf, clv, lv, N, 64, 64);

  // 8. z, res_z, res_z → bf16
  reparam<<<(N * 64 + 255) / 256, 256, 0, stream>>>(mu, lv, eps, zb, N * 64);
  gemm64<<<gB, 256, 0, stream>>>(zb, res_W, res_b, rz, N, 64, 64);
  cvt_bf16<<<(N * 16 + 255) / 256, 256, 0, stream>>>(rz, rzb, N * 16);

  // 9. MFMA decoder
  decoder_mfma<<<(E + 63) / 64, 256, 0, stream>>>(ei, E, rzb, W1t, dec_b1, dec_W2, dec_b2, recon);
}